// Round 7
// baseline (318.676 us; speedup 1.0000x reference)
//
#include <hip/hip_runtime.h>
#include <math.h>

// AttnBlock: GroupNorm(32) -> q,k,v 1x1 -> spatial attention -> proj -> resid.
// Round 16: combine the two proven partial wins. 32 q/wave gives 2-MFMA-per-
// ds_read reuse (halves LDS traffic, R6-verified via conflict counter), and
// 2 waves/SIMD gives overlap (R5-verified). Enablers: single 64KB K/V buffer
// (2 barriers/tile, R3 DMA scheme: K(t+1) after QK barrier, V(t+1) after PV
// barrier) so 2 blocks fit 160KB LDS; KSPLIT=4 so grid=512=2 blocks/CU;
// sn-pipeline dropped (reg relief; cross-block overlap replaces it);
// __launch_bounds__(256,2) pins <=256 regs/wave. accO 128 + a_q 64 + s 32
// ~ 224+scratch. Per-CU LDS traffic: 16MB -> 8MB; MFMA unchanged.

#define BB 4
#define CCH 256
#define NSP 4096
#define EPSV 1e-5f
#define ATTN_SCALE 0.0625f  // 256^-0.5
#define RSQRT2 0.70710678118654752440f
#define KSPLIT 4
#define TILES_PER_PART 16   // 4096 / 64 / KSPLIT

typedef __attribute__((ext_vector_type(8))) short bf16x8;
typedef __attribute__((ext_vector_type(4))) float f32x4;

typedef __attribute__((address_space(1))) void gvoid;
typedef __attribute__((address_space(3))) void lvoid;
__device__ __forceinline__ void dma16(const void* g, void* l) {
  __builtin_amdgcn_global_load_lds((gvoid*)g, (lvoid*)l, 16, 0, 0);
}

__device__ __forceinline__ short f2bf(float f) {
  union { float f; unsigned u; } a; a.f = f;
  unsigned r = a.u + 0x7fffu + ((a.u >> 16) & 1u);  // RTN-even
  return (short)(r >> 16);
}
__device__ __forceinline__ float bf2f(short s) {
  union { unsigned u; float f; } a;
  a.u = ((unsigned)(unsigned short)s) << 16;
  return a.f;
}
__device__ __forceinline__ unsigned cvt_pk_bf16(float lo, float hi) {
  unsigned r;
  asm("v_cvt_pk_bf16_f32 %0, %1, %2" : "=v"(r) : "v"(lo), "v"(hi));
  return r;
}

// ---------------- GroupNorm stats only: mean/rstd per (b,g) ----------------
__global__ __launch_bounds__(256) void gn_stats(
    const float* __restrict__ x, float* __restrict__ stats) {
  int b = blockIdx.x >> 5;
  int g = blockIdx.x & 31;
  size_t base = ((size_t)b * CCH + (size_t)g * 8) * NSP;
  const float4* xv = (const float4*)(x + base);
  int tid = threadIdx.x;
  float s = 0.f, ss = 0.f;
  for (int i = tid; i < 8192; i += 256) {
    float4 v = xv[i];
    s += (v.x + v.y) + (v.z + v.w);
    ss += (v.x * v.x + v.y * v.y) + (v.z * v.z + v.w * v.w);
  }
#pragma unroll
  for (int off = 32; off > 0; off >>= 1) {
    s += __shfl_down(s, off, 64);
    ss += __shfl_down(ss, off, 64);
  }
  __shared__ float rs[4], rss[4];
  int wv = tid >> 6;
  if ((tid & 63) == 0) { rs[wv] = s; rss[wv] = ss; }
  __syncthreads();
  if (tid == 0) {
    float S = rs[0] + rs[1] + rs[2] + rs[3];
    float SS = rss[0] + rss[1] + rss[2] + rss[3];
    float mean = S * (1.f / 32768.f);
    float var = SS * (1.f / 32768.f) - mean * mean;
    stats[(b * 32 + g) * 2 + 0] = mean;
    stats[(b * 32 + g) * 2 + 1] = rsqrtf(var + EPSV);
  }
}

// ------------- prep: W [c][d] fp32 -> [d][c] bf16, 4 weights --------------
__global__ __launch_bounds__(256) void prep_w(
    const float* __restrict__ Wq, const float* __restrict__ Wk,
    const float* __restrict__ Wv, const float* __restrict__ Wp,
    short* __restrict__ wts) {
  __shared__ float T[64][65];
  int c0 = blockIdx.x * 64, d0 = blockIdx.y * 64;
  int wz = blockIdx.z;
  const float* W = (wz == 0) ? Wq : (wz == 1) ? Wk : (wz == 2) ? Wv : Wp;
  short* wt = wts + (size_t)wz * CCH * CCH;
  int tid = threadIdx.x;
#pragma unroll
  for (int i = 0; i < 16; ++i) {
    int idx = tid + 256 * i;
    int row = idx >> 6, col = idx & 63;
    T[row][col] = W[(size_t)(c0 + row) * CCH + d0 + col];
  }
  __syncthreads();
#pragma unroll
  for (int i = 0; i < 16; ++i) {
    int idx = tid + 256 * i;
    int dr = idx >> 6, cc = idx & 63;
    wt[(size_t)(d0 + dr) * CCH + c0 + cc] = f2bf(T[cc][dr]);
  }
}

// ------- qkvg: fused GN-apply + q,k,v projections via bf16 MFMA -----------
// 512 threads / 8 waves: wave w handles rows (w&3)*16.. and d-half (w>>2).
// q/k outputs chunk-swizzled for linear DMA into attn's LDS. v output [c][n]
// stores, within each 64-key tile, key mm at permuted position
// pk = ((mb&1)<<5)|(q<<3)|((mb>>1)<<2)|r, then bank-swizzled by (c&7).
__global__ __launch_bounds__(512) void qkvg_kernel(
    const float* __restrict__ x, const float* __restrict__ stats,
    const float* __restrict__ gw, const float* __restrict__ gb,
    const short* __restrict__ wqt, const short* __restrict__ wkt,
    const short* __restrict__ wvt,
    const float* __restrict__ bq, const float* __restrict__ bk,
    const float* __restrict__ bv,
    short* __restrict__ qo, short* __restrict__ ko, short* __restrict__ vo) {
  __shared__ __align__(16) unsigned char smem[52224];
  float (*Ts)[68] = (float(*)[68])smem;          // 64 x 68 fp32 (17408 B)
  float* aco = (float*)(smem + 17408);           // 256 f32
  float* bco = aco + 256;                        // 256 f32
  short* Hs = (short*)(smem + 19456);            // [64 n][256 c] swizzled bf16
  short* Fo = (short*)smem;                      // epilogue [64 n][264] bf16

  int bx = blockIdx.x;
  int b = bx & 3, n0 = (bx >> 2) * 64;
  int tid = threadIdx.x;
  if (tid < 256) {  // per-channel scale/shift
    int g = tid >> 3;
    float mean = stats[(b * 32 + g) * 2 + 0];
    float rstd = stats[(b * 32 + g) * 2 + 1];
    float a = gw[tid] * rstd;
    aco[tid] = a;
    bco[tid] = gb[tid] - mean * a;
  }
  __syncthreads();
  const float* xb = x + (size_t)b * CCH * NSP;
  // ---- 4 passes: load x chunk, normalize, transpose, bf16 -> swizzled Hs --
  for (int p = 0; p < 4; ++p) {
    int c0 = p * 64;
#pragma unroll
    for (int i = 0; i < 2; ++i) {
      int crow = (tid >> 4) + i * 32;
      int c = c0 + crow;
      float4 v = *(const float4*)&xb[(size_t)c * NSP + n0 + (tid & 15) * 4];
      float a = aco[c], bb = bco[c];
      v.x = v.x * a + bb; v.y = v.y * a + bb;
      v.z = v.z * a + bb; v.w = v.w * a + bb;
      *(float4*)&Ts[crow][(tid & 15) * 4] = v;   // Ts[c_local][n_local]
    }
    __syncthreads();
    {
      int n = tid >> 3, seg = tid & 7;
      int cb = seg * 8;
      bf16x8 r;
#pragma unroll
      for (int j = 0; j < 8; ++j) r[j] = f2bf(Ts[cb + j][n]);
      int chunk = (c0 + cb) >> 3;
      *(bf16x8*)(Hs + n * 256 + ((chunk ^ (n & 7)) * 8)) = r;
    }
    __syncthreads();
  }
  // ---- extract B-frags (rows = this wave's 16 n) ----
  int w = tid >> 6, lane = tid & 63, quad = lane >> 4, l16 = lane & 15;
  int wr = w & 3, h = w >> 2;  // row-group, d-half
  bf16x8 a_h[8];
  {
    int row = wr * 16 + l16;
#pragma unroll
    for (int kc = 0; kc < 8; ++kc)
      a_h[kc] = *(bf16x8*)(Hs + row * 256 + (((kc * 4 + quad) ^ (row & 7)) * 8));
  }
  __syncthreads();  // all waves extracted; smem reusable as Fo
  // ---- 3 projections; wave handles d in [h*128, h*128+128) ----
  for (int op = 0; op < 3; ++op) {
    const short* wt = (op == 0) ? wqt : (op == 1) ? wkt : wvt;
    const float* bias = (op == 0) ? bq : (op == 1) ? bk : bv;
    f32x4 acc[8];
#pragma unroll
    for (int mb = 0; mb < 8; ++mb) acc[mb] = (f32x4){0.f, 0.f, 0.f, 0.f};
#pragma unroll 4
    for (int mb = 0; mb < 8; ++mb) {
      const short* wp = wt + (size_t)((h * 8 + mb) * 16 + l16) * CCH + quad * 8;
#pragma unroll
      for (int kc = 0; kc < 8; ++kc) {
        bf16x8 af = *(const bf16x8*)(wp + kc * 32);
        acc[mb] = __builtin_amdgcn_mfma_f32_16x16x32_bf16(af, a_h[kc], acc[mb], 0, 0, 0);
      }
    }
    int n = n0 + wr * 16 + l16;
    if (op == 2) {  // v: [c][n-permuted] scalar stores
      short* ob = vo + (size_t)b * CCH * NSP;
      int mm = n & 63, m0_ = n & ~63;
      int mb_ = mm >> 4, qq = (mm >> 2) & 3, rr2 = mm & 3;
      int lc = (mb_ & 1) * 4 + qq;          // logical 8-key chunk
      int jj = (mb_ >> 1) * 4 + rr2;        // slot within chunk
      int basen = m0_ + jj;
#pragma unroll
      for (int mb = 0; mb < 8; ++mb)
#pragma unroll
        for (int r = 0; r < 4; ++r) {
          int d = (h * 8 + mb) * 16 + quad * 4 + r;
          ob[(size_t)d * NSP + basen + ((lc ^ (d & 7)) << 3)] =
              f2bf(acc[mb][r] + bias[d]);
        }
    } else {  // q/k: transpose via Fo -> [n][c] b128 stores, chunk-swizzled
      float sc = (op == 0) ? ATTN_SCALE : 1.f;
      int nl = wr * 16 + l16;
#pragma unroll
      for (int mb = 0; mb < 8; ++mb)
#pragma unroll
        for (int r = 0; r < 4; ++r) {
          int d = (h * 8 + mb) * 16 + quad * 4 + r;
          Fo[nl * 264 + d] = f2bf((acc[mb][r] + bias[d]) * sc);
        }
      __syncthreads();
      short* ob = ((op == 0) ? qo : ko) + (size_t)b * NSP * CCH;
      {
        int row = tid >> 3, seg = tid & 7, r7 = row & 7;
        short* dst = ob + (size_t)(n0 + row) * CCH + seg * 32;
#pragma unroll
        for (int i = 0; i < 4; ++i) {
          int xch = seg * 4 + i;
          int cs = (xch & 24) | ((xch & 7) ^ r7);  // source chunk for slot xch
          *(bf16x8*)(dst + i * 8) = *(bf16x8*)(Fo + row * 264 + cs * 8);
        }
      }
      __syncthreads();
    }
  }
}

// ------ flash attention: 4 waves x 32 q/wave, 128 q/block, KSPLIT=4 --------
// Single 64KB K/V buffer, 2 barriers/tile (DMA K(t+1) after QK barrier,
// V(t+1) after PV barrier). 2 blocks/CU, 2 waves/SIMD, <=256 regs/wave.
// Every K/V ds_read feeds 2 MFMAs (query-halves qh).
// XCD swizzle: grp=(b,kh)=bid&15; XCD bid&7 hosts grp and grp+8 (2MB L2 set).
__global__ __launch_bounds__(256, 2) void attn_kernel(
    const short* __restrict__ q, const short* __restrict__ k,
    const short* __restrict__ v, short* __restrict__ po,
    float* __restrict__ pm, float* __restrict__ pl) {
  __shared__ __align__(16) unsigned char smem[65536];   // 64 KB
  short* Ks = (short*)smem;            // [64 m][256 c] swizzled image / Q stage
  short* Vs = (short*)(smem + 32768);  // [256 c][64 m] permuted image
  short* Fo = (short*)smem;            // epilogue [64 n][264 c] bf16

  int bx = blockIdx.x;
  int grp = bx & 15;                // (b,kh) group; bid&7 = XCD
  int b = grp & 3;
  int kh = grp >> 2;                // key quarter (0..3)
  int n0 = (bx >> 4) << 7;          // 128-query block (0..31)
  const short* qb = q + (size_t)b * NSP * CCH;
  const short* kb = k + (size_t)b * NSP * CCH;
  const char*  vbB = (const char*)(v + (size_t)b * CCH * NSP);
  int tid = threadIdx.x;
  int w = tid >> 6, lane = tid & 63, quad = lane >> 4, l16 = lane & 15;
  int mbase = kh * TILES_PER_PART * 64;

  // ---- stage Q in 2 passes of 64 rows through Ks; extract B-frags ----
  // wave w owns queries n0 + (w&1)*32 + qh*16 + l16 at pass p = w>>1
  bf16x8 a_q[2][8];
#pragma unroll
  for (int p = 0; p < 2; ++p) {
#pragma unroll
    for (int i = 0; i < 8; ++i) {
      int off = tid * 16 + i * 4096;
      dma16((const char*)(qb + (size_t)(n0 + p * 64) * CCH) + off,
            (char*)Ks + off);
    }
    __syncthreads();
    if ((w >> 1) == p) {
#pragma unroll
      for (int qh = 0; qh < 2; ++qh) {
        int row = (w & 1) * 32 + qh * 16 + l16;
#pragma unroll
        for (int kc = 0; kc < 8; ++kc)
          a_q[qh][kc] =
              *(bf16x8*)(Ks + row * 256 + (((kc * 4 + quad) ^ (row & 7)) * 8));
      }
    }
    __syncthreads();
  }

  // ---- prologue: K0->Ks, V0->Vs; drain ----
#pragma unroll
  for (int i = 0; i < 8; ++i) {
    int off = tid * 16 + i * 4096;
    dma16((const char*)(kb + (size_t)mbase * CCH) + off, (char*)Ks + off);
    int c = off >> 7, inrow = off & 127;
    dma16(vbB + (size_t)c * (NSP * 2) + (size_t)mbase * 2 + inrow,
          (char*)Vs + off);
  }
  __syncthreads();

  f32x4 accO[16][2];  // ch = cb*16 + quad*4 + r, query = (w&1)*32 + qh*16 + l16
#pragma unroll
  for (int cb = 0; cb < 16; ++cb)
#pragma unroll
    for (int qh = 0; qh < 2; ++qh) accO[cb][qh] = (f32x4){0.f, 0.f, 0.f, 0.f};
  float m_run[2] = {-1e30f, -1e30f}, l_run[2] = {0.f, 0.f};
  int pc0 = quad ^ (l16 & 7);        // V chunk for key-group 0 (loop-invariant)
  int pc1 = (4 + quad) ^ (l16 & 7);  // key-group 1

#pragma unroll 1
  for (int t = 0; t < TILES_PER_PART; ++t) {
    // ---- S^T = K Q^T : each kf read feeds 2 MFMAs ----
    f32x4 s[4][2];
#pragma unroll
    for (int mb = 0; mb < 4; ++mb)
#pragma unroll
      for (int qh = 0; qh < 2; ++qh) s[mb][qh] = (f32x4){0.f, 0.f, 0.f, 0.f};
    __builtin_amdgcn_s_setprio(1);
#pragma unroll
    for (int kc = 0; kc < 8; ++kc) {
#pragma unroll
      for (int mb = 0; mb < 4; ++mb) {
        int row = mb * 16 + l16;
        bf16x8 kf = *(bf16x8*)(Ks + row * 256 + (((kc * 4 + quad) ^ (row & 7)) * 8));
#pragma unroll
        for (int qh = 0; qh < 2; ++qh)
          s[mb][qh] = __builtin_amdgcn_mfma_f32_16x16x32_bf16(
              kf, a_q[qh][kc], s[mb][qh], 0, 0, 0);
      }
    }
    __builtin_amdgcn_s_setprio(0);
    __syncthreads();  // Ks readers done (also drains V(t) DMA)
    if (t + 1 < TILES_PER_PART) {  // DMA K(t+1): overlaps softmax + PV
      const char* kp = (const char*)(kb + (size_t)(mbase + (t + 1) * 64) * CCH);
#pragma unroll
      for (int i = 0; i < 8; ++i) {
        int off = tid * 16 + i * 4096;
        dma16(kp + off, (char*)Ks + off);
      }
    }
    // ---- online softmax: per-lane scalar stats, 2 query-halves ----
    float mx[2];
#pragma unroll
    for (int qh = 0; qh < 2; ++qh) {
      float m = -1e30f;
#pragma unroll
      for (int mb = 0; mb < 4; ++mb)
#pragma unroll
        for (int r = 0; r < 4; ++r) m = fmaxf(m, s[mb][qh][r]);
      m = fmaxf(m, __shfl_xor(m, 16));
      m = fmaxf(m, __shfl_xor(m, 32));
      mx[qh] = m;
    }
    bool grow = (mx[0] - m_run[0] > 8.f) || (mx[1] - m_run[1] > 8.f);
    if (__any(grow)) {               // T13: rescale only when max grows >8
#pragma unroll
      for (int qh = 0; qh < 2; ++qh) {
        float mnew = fmaxf(m_run[qh], mx[qh]);
        float alpha = __expf(m_run[qh] - mnew);
#pragma unroll
        for (int cb = 0; cb < 16; ++cb) accO[cb][qh] *= alpha;
        l_run[qh] *= alpha;
        m_run[qh] = mnew;
      }
    }
#pragma unroll
    for (int qh = 0; qh < 2; ++qh) {
      float ls = 0.f;
#pragma unroll
      for (int mb = 0; mb < 4; ++mb)
#pragma unroll
        for (int r = 0; r < 4; ++r) {
          float p = __expf(s[mb][qh][r] - m_run[qh]);   // bounded by e^8
          ls += p;
          s[mb][qh][r] = p;
        }
      ls += __shfl_xor(ls, 16);
      ls += __shfl_xor(ls, 32);
      l_run[qh] += ls;
    }
    // ---- pack P into 16x16x32 B-frags (V key-permutation makes it direct) --
    union { unsigned u[4]; bf16x8 v; } pw0[2], pw1[2];
#pragma unroll
    for (int qh = 0; qh < 2; ++qh) {
      pw0[qh].u[0] = cvt_pk_bf16(s[0][qh][0], s[0][qh][1]);
      pw0[qh].u[1] = cvt_pk_bf16(s[0][qh][2], s[0][qh][3]);
      pw0[qh].u[2] = cvt_pk_bf16(s[2][qh][0], s[2][qh][1]);
      pw0[qh].u[3] = cvt_pk_bf16(s[2][qh][2], s[2][qh][3]);
      pw1[qh].u[0] = cvt_pk_bf16(s[1][qh][0], s[1][qh][1]);
      pw1[qh].u[1] = cvt_pk_bf16(s[1][qh][2], s[1][qh][3]);
      pw1[qh].u[2] = cvt_pk_bf16(s[3][qh][0], s[3][qh][1]);
      pw1[qh].u[3] = cvt_pk_bf16(s[3][qh][2], s[3][qh][3]);
    }
    // ---- O^T += V P^T : each vf read feeds 2 MFMAs ----
    __builtin_amdgcn_s_setprio(1);
#pragma unroll
    for (int cb = 0; cb < 16; ++cb) {
      bf16x8 vf = *(bf16x8*)(Vs + (cb * 16 + l16) * 64 + pc0 * 8);
#pragma unroll
      for (int qh = 0; qh < 2; ++qh)
        accO[cb][qh] = __builtin_amdgcn_mfma_f32_16x16x32_bf16(
            vf, pw0[qh].v, accO[cb][qh], 0, 0, 0);
    }
#pragma unroll
    for (int cb = 0; cb < 16; ++cb) {
      bf16x8 vf = *(bf16x8*)(Vs + (cb * 16 + l16) * 64 + pc1 * 8);
#pragma unroll
      for (int qh = 0; qh < 2; ++qh)
        accO[cb][qh] = __builtin_amdgcn_mfma_f32_16x16x32_bf16(
            vf, pw1[qh].v, accO[cb][qh], 0, 0, 0);
    }
    __builtin_amdgcn_s_setprio(0);
    __syncthreads();  // Vs readers done (also drains K(t+1) DMA)
    if (t + 1 < TILES_PER_PART) {  // DMA V(t+1): overlaps next QK
      int m0 = mbase + (t + 1) * 64;
#pragma unroll
      for (int i = 0; i < 8; ++i) {
        int off = tid * 16 + i * 4096;
        int c = off >> 7, inrow = off & 127;
        dma16(vbB + (size_t)c * (NSP * 2) + (size_t)m0 * 2 + inrow,
              (char*)Vs + off);
      }
    }
  }
  // ---- stats ----
  size_t sbase = ((size_t)kh * BB + b) * NSP + n0;
  if (quad == 0) {
#pragma unroll
    for (int qh = 0; qh < 2; ++qh) {
      pm[sbase + (w & 1) * 32 + (w >> 1) * 64 + qh * 16 + l16] = m_run[qh];
      pl[sbase + (w & 1) * 32 + (w >> 1) * 64 + qh * 16 + l16] = l_run[qh];
    }
  }
  // ---- epilogue: normalized bf16 O -> po [kh][b][n][c], LDS transpose ----
  short* ob = po + ((size_t)kh * BB + b) * NSP * CCH;
#pragma unroll
  for (int p = 0; p < 2; ++p) {
    __syncthreads();
    if ((w >> 1) == p) {
#pragma unroll
      for (int qh = 0; qh < 2; ++qh) {
        int nloc = (w & 1) * 32 + qh * 16 + l16;
        float linv = 1.f / l_run[qh];
#pragma unroll
        for (int cb = 0; cb < 16; ++cb)
#pragma unroll
          for (int r = 0; r < 4; ++r)
            Fo[nloc * 264 + cb * 16 + quad * 4 + r] =
                f2bf(accO[cb][qh][r] * linv);
      }
    }
    __syncthreads();
    int row = tid >> 2, seg = tid & 3;
    short* dst = ob + (size_t)(n0 + p * 64 + row) * CCH + seg * 64;
#pragma unroll
    for (int i = 0; i < 8; ++i)
      *(bf16x8*)(dst + i * 8) = *(bf16x8*)(Fo + row * 264 + seg * 64 + i * 8);
  }
}

// ------- proj: frag-direct MFMA, KSPLIT-way merge in registers, +bias+resid -
__global__ __launch_bounds__(256) void proj_kernel(
    const short* __restrict__ po, const float* __restrict__ pm,
    const float* __restrict__ pl, const short* __restrict__ wpt,
    const float* __restrict__ bp, const float* __restrict__ x,
    float* __restrict__ out) {
  int n0 = blockIdx.x * 64;
  int dh = blockIdx.y * 128;
  int b = blockIdx.z;
  int tid = threadIdx.x;
  int w = tid >> 6, lane = tid & 63, quad = lane >> 4, l16 = lane & 15;
  int n = n0 + w * 16 + l16;

  float wgt[KSPLIT];
  {
    float m[KSPLIT];
    float M = -1e30f;
#pragma unroll
    for (int s = 0; s < KSPLIT; ++s) {
      m[s] = pm[((size_t)s * BB + b) * NSP + n];
      M = fmaxf(M, m[s]);
    }
    float wsum = 0.f;
#pragma unroll
    for (int s = 0; s < KSPLIT; ++s) {
      wgt[s] = __expf(m[s] - M) * pl[((size_t)s * BB + b) * NSP + n];
      wsum += wgt[s];
    }
    float linv = 1.f / wsum;
#pragma unroll
    for (int s = 0; s < KSPLIT; ++s) wgt[s] *= linv;
  }

  f32x4 acc[8];
#pragma unroll
  for (int mb = 0; mb < 8; ++mb) acc[mb] = (f32x4){0.f, 0.f, 0.f, 0.f};

  const short* pob = po + ((size_t)b * NSP + n) * CCH;
#pragma unroll 2
  for (int kc = 0; kc < 8; ++kc) {
    int coff = kc * 32 + quad * 8;
    float e[8];
#pragma unroll
    for (int i = 0; i < 8; ++i) e[i] = 0.f;
#pragma unroll
    for (int s = 0; s < KSPLIT; ++s) {
      bf16x8 f = *(const bf16x8*)(pob + (size_t)s * BB * NSP * CCH + coff);
#pragma unroll
      for (int i = 0; i < 8; ++i) e[i] += wgt[s] * bf2f(f[i]);
    }
    bf16x8 bm;
#pragma unroll
    for (int i = 0; i < 8; ++i) bm[i] = f2bf(e[i]);
#pragma unroll
    for (int mb = 0; mb < 8; ++mb) {
      bf16x8 af = *(const bf16x8*)(wpt + (size_t)(dh + mb * 16 + l16) * CCH + coff);
      acc[mb] = __builtin_amdgcn_mfma_f32_16x16x32_bf16(af, bm, acc[mb], 0, 0, 0);
    }
  }
#pragma unroll
  for (int mb = 0; mb < 8; ++mb) {
#pragma unroll
    for (int r = 0; r < 4; ++r) {
      int d = dh + mb * 16 + quad * 4 + r;
      size_t off = ((size_t)b * CCH + d) * NSP + n;
      out[off] = (acc[mb][r] + bp[d] + x[off]) * RSQRT2;
    }
  }
}

extern "C" void kernel_launch(void* const* d_in, const int* in_sizes, int n_in,
                              void* d_out, int out_size, void* d_ws, size_t ws_size,
                              hipStream_t stream) {
  const float* x  = (const float*)d_in[0];
  const float* gw = (const float*)d_in[1];
  const float* gb = (const float*)d_in[2];
  const float* Wq = (const float*)d_in[3];
  const float* bq = (const float*)d_in[4];
  const float* Wk = (const float*)d_in[5];
  const float* bk = (const float*)d_in[6];
  const float* Wv = (const float*)d_in[7];
  const float* bv = (const float*)d_in[8];
  const float* Wp = (const float*)d_in[9];
  const float* bp = (const float*)d_in[10];
  float* out = (float*)d_out;

  const size_t SZ = (size_t)BB * CCH * NSP;  // 4.19M elems
  short* qb  = (short*)d_ws;                 // bf16 [b][n][c] swizzled, scaled
  short* kb  = qb + SZ;                      // bf16 [b][n][c] swizzled
  short* vb  = kb + SZ;                      // bf16 [b][c][n] permuted
  short* poT = vb + SZ;                      // bf16 [KSPLIT][b][n][c] normalized
  float* pm  = (float*)(poT + (size_t)KSPLIT * SZ);  // [KSPLIT][b][n]
  float* pl  = pm + (size_t)KSPLIT * BB * NSP;
  float* stats = pl + (size_t)KSPLIT * BB * NSP;     // [b][32][2]
  short* wts = (short*)(stats + BB * 64);            // bf16 [4][256][256]
  short* wqt = wts;
  short* wkt = wts + (size_t)CCH * CCH;
  short* wvt = wts + (size_t)2 * CCH * CCH;
  short* wpt = wts + (size_t)3 * CCH * CCH;

  gn_stats<<<dim3(BB * 32), dim3(256), 0, stream>>>(x, stats);
  prep_w<<<dim3(4, 4, 4), dim3(256), 0, stream>>>(Wq, Wk, Wv, Wp, wts);
  qkvg_kernel<<<dim3(256), dim3(512), 0, stream>>>(
      x, stats, gw, gb, wqt, wkt, wvt, bq, bk, bv, qb, kb, vb);
  attn_kernel<<<dim3(BB * 32 * KSPLIT), dim3(256), 0, stream>>>(
      qb, kb, vb, poT, pm, pl);
  proj_kernel<<<dim3(64, 2, BB), dim3(256), 0, stream>>>(
      poT, pm, pl, wpt, bp, x, out);
}

// Round 8
// 283.201 us; speedup vs baseline: 1.1253x; 1.1253x over previous
//
#include <hip/hip_runtime.h>
#include <math.h>

// AttnBlock: GroupNorm(32) -> q,k,v 1x1 -> spatial attention -> proj -> resid.
// Round 17: attn = 4-wave blocks x 16 q/wave (64 q/block), KSPLIT=2, grid 512
// = 2 INDEPENDENT blocks/CU. R7 proved 2 blocks/CU reachable but 32q/wave
// spilled (~150 VALU regs vs 128 cap); 16q/wave keeps R5's proven ~160-reg
// shape -> no spills, and the two unsynchronized blocks overlap each other's
// softmax VALU bursts and barrier stalls (R5's single 8-wave block aligns
// them). Single 64KB K/V buffer, R3-proven 2-barrier/tile DMA schedule.
// Everything else (qkvg 512-thr, proj, layouts, swizzles) = R5 best (275us).

#define BB 4
#define CCH 256
#define NSP 4096
#define EPSV 1e-5f
#define ATTN_SCALE 0.0625f  // 256^-0.5
#define RSQRT2 0.70710678118654752440f
#define KSPLIT 2
#define TILES_PER_PART 32   // 4096 / 64 / KSPLIT

typedef __attribute__((ext_vector_type(8))) short bf16x8;
typedef __attribute__((ext_vector_type(4))) float f32x4;

typedef __attribute__((address_space(1))) void gvoid;
typedef __attribute__((address_space(3))) void lvoid;
__device__ __forceinline__ void dma16(const void* g, void* l) {
  __builtin_amdgcn_global_load_lds((gvoid*)g, (lvoid*)l, 16, 0, 0);
}

__device__ __forceinline__ short f2bf(float f) {
  union { float f; unsigned u; } a; a.f = f;
  unsigned r = a.u + 0x7fffu + ((a.u >> 16) & 1u);  // RTN-even
  return (short)(r >> 16);
}
__device__ __forceinline__ float bf2f(short s) {
  union { unsigned u; float f; } a;
  a.u = ((unsigned)(unsigned short)s) << 16;
  return a.f;
}
__device__ __forceinline__ unsigned cvt_pk_bf16(float lo, float hi) {
  unsigned r;
  asm("v_cvt_pk_bf16_f32 %0, %1, %2" : "=v"(r) : "v"(lo), "v"(hi));
  return r;
}

// ---------------- GroupNorm stats only: mean/rstd per (b,g) ----------------
__global__ __launch_bounds__(256) void gn_stats(
    const float* __restrict__ x, float* __restrict__ stats) {
  int b = blockIdx.x >> 5;
  int g = blockIdx.x & 31;
  size_t base = ((size_t)b * CCH + (size_t)g * 8) * NSP;
  const float4* xv = (const float4*)(x + base);
  int tid = threadIdx.x;
  float s = 0.f, ss = 0.f;
  for (int i = tid; i < 8192; i += 256) {
    float4 v = xv[i];
    s += (v.x + v.y) + (v.z + v.w);
    ss += (v.x * v.x + v.y * v.y) + (v.z * v.z + v.w * v.w);
  }
#pragma unroll
  for (int off = 32; off > 0; off >>= 1) {
    s += __shfl_down(s, off, 64);
    ss += __shfl_down(ss, off, 64);
  }
  __shared__ float rs[4], rss[4];
  int wv = tid >> 6;
  if ((tid & 63) == 0) { rs[wv] = s; rss[wv] = ss; }
  __syncthreads();
  if (tid == 0) {
    float S = rs[0] + rs[1] + rs[2] + rs[3];
    float SS = rss[0] + rss[1] + rss[2] + rss[3];
    float mean = S * (1.f / 32768.f);
    float var = SS * (1.f / 32768.f) - mean * mean;
    stats[(b * 32 + g) * 2 + 0] = mean;
    stats[(b * 32 + g) * 2 + 1] = rsqrtf(var + EPSV);
  }
}

// ------------- prep: W [c][d] fp32 -> [d][c] bf16, 4 weights --------------
__global__ __launch_bounds__(256) void prep_w(
    const float* __restrict__ Wq, const float* __restrict__ Wk,
    const float* __restrict__ Wv, const float* __restrict__ Wp,
    short* __restrict__ wts) {
  __shared__ float T[64][65];
  int c0 = blockIdx.x * 64, d0 = blockIdx.y * 64;
  int wz = blockIdx.z;
  const float* W = (wz == 0) ? Wq : (wz == 1) ? Wk : (wz == 2) ? Wv : Wp;
  short* wt = wts + (size_t)wz * CCH * CCH;
  int tid = threadIdx.x;
#pragma unroll
  for (int i = 0; i < 16; ++i) {
    int idx = tid + 256 * i;
    int row = idx >> 6, col = idx & 63;
    T[row][col] = W[(size_t)(c0 + row) * CCH + d0 + col];
  }
  __syncthreads();
#pragma unroll
  for (int i = 0; i < 16; ++i) {
    int idx = tid + 256 * i;
    int dr = idx >> 6, cc = idx & 63;
    wt[(size_t)(d0 + dr) * CCH + c0 + cc] = f2bf(T[cc][dr]);
  }
}

// ------- qkvg: fused GN-apply + q,k,v projections via bf16 MFMA -----------
// 512 threads / 8 waves: wave w handles rows (w&3)*16.. and d-half (w>>2).
// q/k outputs chunk-swizzled for linear DMA into attn's LDS. v output [c][n]
// stores, within each 64-key tile, key mm at permuted position
// pk = ((mb&1)<<5)|(q<<3)|((mb>>1)<<2)|r, then bank-swizzled by (c&7).
__global__ __launch_bounds__(512) void qkvg_kernel(
    const float* __restrict__ x, const float* __restrict__ stats,
    const float* __restrict__ gw, const float* __restrict__ gb,
    const short* __restrict__ wqt, const short* __restrict__ wkt,
    const short* __restrict__ wvt,
    const float* __restrict__ bq, const float* __restrict__ bk,
    const float* __restrict__ bv,
    short* __restrict__ qo, short* __restrict__ ko, short* __restrict__ vo) {
  __shared__ __align__(16) unsigned char smem[52224];
  float (*Ts)[68] = (float(*)[68])smem;          // 64 x 68 fp32 (17408 B)
  float* aco = (float*)(smem + 17408);           // 256 f32
  float* bco = aco + 256;                        // 256 f32
  short* Hs = (short*)(smem + 19456);            // [64 n][256 c] swizzled bf16
  short* Fo = (short*)smem;                      // epilogue [64 n][264] bf16

  int bx = blockIdx.x;
  int b = bx & 3, n0 = (bx >> 2) * 64;
  int tid = threadIdx.x;
  if (tid < 256) {  // per-channel scale/shift
    int g = tid >> 3;
    float mean = stats[(b * 32 + g) * 2 + 0];
    float rstd = stats[(b * 32 + g) * 2 + 1];
    float a = gw[tid] * rstd;
    aco[tid] = a;
    bco[tid] = gb[tid] - mean * a;
  }
  __syncthreads();
  const float* xb = x + (size_t)b * CCH * NSP;
  // ---- 4 passes: load x chunk, normalize, transpose, bf16 -> swizzled Hs --
  for (int p = 0; p < 4; ++p) {
    int c0 = p * 64;
#pragma unroll
    for (int i = 0; i < 2; ++i) {
      int crow = (tid >> 4) + i * 32;
      int c = c0 + crow;
      float4 v = *(const float4*)&xb[(size_t)c * NSP + n0 + (tid & 15) * 4];
      float a = aco[c], bb = bco[c];
      v.x = v.x * a + bb; v.y = v.y * a + bb;
      v.z = v.z * a + bb; v.w = v.w * a + bb;
      *(float4*)&Ts[crow][(tid & 15) * 4] = v;   // Ts[c_local][n_local]
    }
    __syncthreads();
    {
      int n = tid >> 3, seg = tid & 7;
      int cb = seg * 8;
      bf16x8 r;
#pragma unroll
      for (int j = 0; j < 8; ++j) r[j] = f2bf(Ts[cb + j][n]);
      int chunk = (c0 + cb) >> 3;
      *(bf16x8*)(Hs + n * 256 + ((chunk ^ (n & 7)) * 8)) = r;
    }
    __syncthreads();
  }
  // ---- extract B-frags (rows = this wave's 16 n) ----
  int w = tid >> 6, lane = tid & 63, quad = lane >> 4, l16 = lane & 15;
  int wr = w & 3, h = w >> 2;  // row-group, d-half
  bf16x8 a_h[8];
  {
    int row = wr * 16 + l16;
#pragma unroll
    for (int kc = 0; kc < 8; ++kc)
      a_h[kc] = *(bf16x8*)(Hs + row * 256 + (((kc * 4 + quad) ^ (row & 7)) * 8));
  }
  __syncthreads();  // all waves extracted; smem reusable as Fo
  // ---- 3 projections; wave handles d in [h*128, h*128+128) ----
  for (int op = 0; op < 3; ++op) {
    const short* wt = (op == 0) ? wqt : (op == 1) ? wkt : wvt;
    const float* bias = (op == 0) ? bq : (op == 1) ? bk : bv;
    f32x4 acc[8];
#pragma unroll
    for (int mb = 0; mb < 8; ++mb) acc[mb] = (f32x4){0.f, 0.f, 0.f, 0.f};
#pragma unroll 4
    for (int mb = 0; mb < 8; ++mb) {
      const short* wp = wt + (size_t)((h * 8 + mb) * 16 + l16) * CCH + quad * 8;
#pragma unroll
      for (int kc = 0; kc < 8; ++kc) {
        bf16x8 af = *(const bf16x8*)(wp + kc * 32);
        acc[mb] = __builtin_amdgcn_mfma_f32_16x16x32_bf16(af, a_h[kc], acc[mb], 0, 0, 0);
      }
    }
    int n = n0 + wr * 16 + l16;
    if (op == 2) {  // v: [c][n-permuted] scalar stores
      short* ob = vo + (size_t)b * CCH * NSP;
      int mm = n & 63, m0_ = n & ~63;
      int mb_ = mm >> 4, qq = (mm >> 2) & 3, rr2 = mm & 3;
      int lc = (mb_ & 1) * 4 + qq;          // logical 8-key chunk
      int jj = (mb_ >> 1) * 4 + rr2;        // slot within chunk
      int basen = m0_ + jj;
#pragma unroll
      for (int mb = 0; mb < 8; ++mb)
#pragma unroll
        for (int r = 0; r < 4; ++r) {
          int d = (h * 8 + mb) * 16 + quad * 4 + r;
          ob[(size_t)d * NSP + basen + ((lc ^ (d & 7)) << 3)] =
              f2bf(acc[mb][r] + bias[d]);
        }
    } else {  // q/k: transpose via Fo -> [n][c] b128 stores, chunk-swizzled
      float sc = (op == 0) ? ATTN_SCALE : 1.f;
      int nl = wr * 16 + l16;
#pragma unroll
      for (int mb = 0; mb < 8; ++mb)
#pragma unroll
        for (int r = 0; r < 4; ++r) {
          int d = (h * 8 + mb) * 16 + quad * 4 + r;
          Fo[nl * 264 + d] = f2bf((acc[mb][r] + bias[d]) * sc);
        }
      __syncthreads();
      short* ob = ((op == 0) ? qo : ko) + (size_t)b * NSP * CCH;
      {
        int row = tid >> 3, seg = tid & 7, r7 = row & 7;
        short* dst = ob + (size_t)(n0 + row) * CCH + seg * 32;
#pragma unroll
        for (int i = 0; i < 4; ++i) {
          int xch = seg * 4 + i;
          int cs = (xch & 24) | ((xch & 7) ^ r7);  // source chunk for slot xch
          *(bf16x8*)(dst + i * 8) = *(bf16x8*)(Fo + row * 264 + cs * 8);
        }
      }
      __syncthreads();
    }
  }
}

// ------ flash attention: 4 waves x 16 q/wave, 64 q/block, KSPLIT=2 ---------
// 2 independent blocks/CU (LDS 2x64KB, regs ~160/wave). Single K/V buffer,
// 2 barriers/tile; DMA K(t+1) after QK barrier, V(t+1) after PV barrier.
// XCD swizzle: (b,kh) group = bid&7 = XCD under round-robin dispatch.
__global__ __launch_bounds__(256, 2) void attn_kernel(
    const short* __restrict__ q, const short* __restrict__ k,
    const short* __restrict__ v, short* __restrict__ po,
    float* __restrict__ pm, float* __restrict__ pl) {
  __shared__ __align__(16) unsigned char smem[65536];   // 64 KB
  short* Ks = (short*)smem;            // [64 m][256 c] swizzled / Q stage
  short* Vs = (short*)(smem + 32768);  // [256 c][64 m] permuted image
  short* Fo = (short*)smem;            // epilogue [64 n][264 c] bf16

  int bx = blockIdx.x;
  int grp = bx & 7;                 // XCD id under round-robin dispatch
  int b = grp & 3;
  int kh = grp >> 2;                // key half
  int n0 = (bx >> 3) << 6;          // 64-query block (0..63)
  const short* qb = q + (size_t)b * NSP * CCH;
  const short* kb = k + (size_t)b * NSP * CCH;
  const char*  vbB = (const char*)(v + (size_t)b * CCH * NSP);
  int tid = threadIdx.x;
  int w = tid >> 6, lane = tid & 63, quad = lane >> 4, l16 = lane & 15;
  int mbase = kh * TILES_PER_PART * 64;

  // ---- stage Q (one 32KB pass through Ks); extract B-frags ----
#pragma unroll
  for (int i = 0; i < 8; ++i) {
    int off = tid * 16 + i * 4096;
    dma16((const char*)(qb + (size_t)n0 * CCH) + off, (char*)Ks + off);
  }
  __syncthreads();
  bf16x8 a_q[8];
  {
    int row = w * 16 + l16;
#pragma unroll
    for (int kc = 0; kc < 8; ++kc)
      a_q[kc] = *(bf16x8*)(Ks + row * 256 + (((kc * 4 + quad) ^ (row & 7)) * 8));
  }
  __syncthreads();

  // ---- prologue: K0->Ks, V0->Vs; drain ----
#pragma unroll
  for (int i = 0; i < 8; ++i) {
    int off = tid * 16 + i * 4096;
    dma16((const char*)(kb + (size_t)mbase * CCH) + off, (char*)Ks + off);
    int c = off >> 7, inrow = off & 127;
    dma16(vbB + (size_t)c * (NSP * 2) + (size_t)mbase * 2 + inrow,
          (char*)Vs + off);
  }
  __syncthreads();

  f32x4 accO[16];  // O^T C-layout: ch = cb*16 + quad*4 + r, query = w*16+l16
#pragma unroll
  for (int cb = 0; cb < 16; ++cb) accO[cb] = (f32x4){0.f, 0.f, 0.f, 0.f};
  float m_run = -1e30f, l_run = 0.f;
  int pc0 = quad ^ (l16 & 7);        // V chunk for key-group 0 (loop-invariant)
  int pc1 = (4 + quad) ^ (l16 & 7);  // key-group 1

#pragma unroll 1
  for (int t = 0; t < TILES_PER_PART; ++t) {
    // ---- S^T = K Q^T : rows = 64 keys, cols = this wave's 16 queries ----
    f32x4 s[4];
#pragma unroll
    for (int mb = 0; mb < 4; ++mb) s[mb] = (f32x4){0.f, 0.f, 0.f, 0.f};
    __builtin_amdgcn_s_setprio(1);
#pragma unroll
    for (int kc = 0; kc < 8; ++kc) {
#pragma unroll
      for (int mb = 0; mb < 4; ++mb) {
        int row = mb * 16 + l16;
        bf16x8 kf = *(bf16x8*)(Ks + row * 256 + (((kc * 4 + quad) ^ (row & 7)) * 8));
        s[mb] = __builtin_amdgcn_mfma_f32_16x16x32_bf16(kf, a_q[kc], s[mb], 0, 0, 0);
      }
    }
    __builtin_amdgcn_s_setprio(0);
    __syncthreads();  // Ks readers done (drains V(t) DMA too)
    if (t + 1 < TILES_PER_PART) {  // DMA K(t+1): overlaps softmax + PV
      const char* kp = (const char*)(kb + (size_t)(mbase + (t + 1) * 64) * CCH);
#pragma unroll
      for (int i = 0; i < 8; ++i) {
        int off = tid * 16 + i * 4096;
        dma16(kp + off, (char*)Ks + off);
      }
    }
    // ---- online softmax: per-lane scalar stats (one query per lane) ----
    float mx = -1e30f;
#pragma unroll
    for (int mb = 0; mb < 4; ++mb)
#pragma unroll
      for (int r = 0; r < 4; ++r) mx = fmaxf(mx, s[mb][r]);
    mx = fmaxf(mx, __shfl_xor(mx, 16));
    mx = fmaxf(mx, __shfl_xor(mx, 32));
    if (!__all(mx - m_run <= 8.f)) {   // T13: rescale only when max grows >8
      float mnew = fmaxf(m_run, mx);
      float alpha = __expf(m_run - mnew);
#pragma unroll
      for (int cb = 0; cb < 16; ++cb) accO[cb] *= alpha;
      l_run *= alpha;
      m_run = mnew;
    }
    float ls = 0.f;
#pragma unroll
    for (int mb = 0; mb < 4; ++mb)
#pragma unroll
      for (int r = 0; r < 4; ++r) {
        float p = __expf(s[mb][r] - m_run);   // bounded by e^8
        ls += p;
        s[mb][r] = p;
      }
    ls += __shfl_xor(ls, 16);
    ls += __shfl_xor(ls, 32);
    l_run += ls;
    // ---- pack P into 16x16x32 B-frags (key permutation makes this direct) --
    union { unsigned u[4]; bf16x8 v; } pw0, pw1;
    pw0.u[0] = cvt_pk_bf16(s[0][0], s[0][1]);
    pw0.u[1] = cvt_pk_bf16(s[0][2], s[0][3]);
    pw0.u[2] = cvt_pk_bf16(s[2][0], s[2][1]);
    pw0.u[3] = cvt_pk_bf16(s[2][2], s[2][3]);
    pw1.u[0] = cvt_pk_bf16(s[1][0], s[1][1]);
    pw1.u[1] = cvt_pk_bf16(s[1][2], s[1][3]);
    pw1.u[2] = cvt_pk_bf16(s[3][0], s[3][1]);
    pw1.u[3] = cvt_pk_bf16(s[3][2], s[3][3]);
    // ---- O^T += V P^T : full-rate 16x16x32, b128 V reads ----
    __builtin_amdgcn_s_setprio(1);
#pragma unroll
    for (int cb = 0; cb < 16; ++cb) {
      bf16x8 vf = *(bf16x8*)(Vs + (cb * 16 + l16) * 64 + pc0 * 8);
      accO[cb] = __builtin_amdgcn_mfma_f32_16x16x32_bf16(vf, pw0.v, accO[cb], 0, 0, 0);
    }
#pragma unroll
    for (int cb = 0; cb < 16; ++cb) {
      bf16x8 vf = *(bf16x8*)(Vs + (cb * 16 + l16) * 64 + pc1 * 8);
      accO[cb] = __builtin_amdgcn_mfma_f32_16x16x32_bf16(vf, pw1.v, accO[cb], 0, 0, 0);
    }
    __builtin_amdgcn_s_setprio(0);
    __syncthreads();  // Vs readers done (drains K(t+1) DMA too)
    if (t + 1 < TILES_PER_PART) {  // DMA V(t+1): overlaps next QK + softmax
      int m0 = mbase + (t + 1) * 64;
#pragma unroll
      for (int i = 0; i < 8; ++i) {
        int off = tid * 16 + i * 4096;
        int c = off >> 7, inrow = off & 127;
        dma16(vbB + (size_t)c * (NSP * 2) + (size_t)m0 * 2 + inrow,
              (char*)Vs + off);
      }
    }
  }
  // ---- stats ----
  size_t sbase = ((size_t)kh * BB + b) * NSP + n0;
  if (quad == 0) {
    pm[sbase + w * 16 + l16] = m_run;
    pl[sbase + w * 16 + l16] = l_run;
  }
  // ---- epilogue: normalized bf16 O -> po [kh][b][n][c], LDS transpose ----
  float linv = 1.f / l_run;
  short* ob = po + ((size_t)kh * BB + b) * NSP * CCH;
  {
    int nloc = w * 16 + l16;
#pragma unroll
    for (int cb = 0; cb < 16; ++cb)
#pragma unroll
      for (int r = 0; r < 4; ++r)
        Fo[nloc * 264 + cb * 16 + quad * 4 + r] = f2bf(accO[cb][r] * linv);
  }
  __syncthreads();
  {
    int row = tid >> 2, seg = tid & 3;
    short* dst = ob + (size_t)(n0 + row) * CCH + seg * 64;
#pragma unroll
    for (int i = 0; i < 8; ++i)
      *(bf16x8*)(dst + i * 8) = *(bf16x8*)(Fo + row * 264 + seg * 64 + i * 8);
  }
}

// ------- proj: frag-direct MFMA, KSPLIT-way merge in registers, +bias+resid -
__global__ __launch_bounds__(256) void proj_kernel(
    const short* __restrict__ po, const float* __restrict__ pm,
    const float* __restrict__ pl, const short* __restrict__ wpt,
    const float* __restrict__ bp, const float* __restrict__ x,
    float* __restrict__ out) {
  int n0 = blockIdx.x * 64;
  int dh = blockIdx.y * 128;
  int b = blockIdx.z;
  int tid = threadIdx.x;
  int w = tid >> 6, lane = tid & 63, quad = lane >> 4, l16 = lane & 15;
  int n = n0 + w * 16 + l16;

  float wgt[KSPLIT];
  {
    float m[KSPLIT];
    float M = -1e30f;
#pragma unroll
    for (int s = 0; s < KSPLIT; ++s) {
      m[s] = pm[((size_t)s * BB + b) * NSP + n];
      M = fmaxf(M, m[s]);
    }
    float wsum = 0.f;
#pragma unroll
    for (int s = 0; s < KSPLIT; ++s) {
      wgt[s] = __expf(m[s] - M) * pl[((size_t)s * BB + b) * NSP + n];
      wsum += wgt[s];
    }
    float linv = 1.f / wsum;
#pragma unroll
    for (int s = 0; s < KSPLIT; ++s) wgt[s] *= linv;
  }

  f32x4 acc[8];
#pragma unroll
  for (int mb = 0; mb < 8; ++mb) acc[mb] = (f32x4){0.f, 0.f, 0.f, 0.f};

  const short* pob = po + ((size_t)b * NSP + n) * CCH;
#pragma unroll 2
  for (int kc = 0; kc < 8; ++kc) {
    int coff = kc * 32 + quad * 8;
    float e[8];
#pragma unroll
    for (int i = 0; i < 8; ++i) e[i] = 0.f;
#pragma unroll
    for (int s = 0; s < KSPLIT; ++s) {
      bf16x8 f = *(const bf16x8*)(pob + (size_t)s * BB * NSP * CCH + coff);
#pragma unroll
      for (int i = 0; i < 8; ++i) e[i] += wgt[s] * bf2f(f[i]);
    }
    bf16x8 bm;
#pragma unroll
    for (int i = 0; i < 8; ++i) bm[i] = f2bf(e[i]);
#pragma unroll
    for (int mb = 0; mb < 8; ++mb) {
      bf16x8 af = *(const bf16x8*)(wpt + (size_t)(dh + mb * 16 + l16) * CCH + coff);
      acc[mb] = __builtin_amdgcn_mfma_f32_16x16x32_bf16(af, bm, acc[mb], 0, 0, 0);
    }
  }
#pragma unroll
  for (int mb = 0; mb < 8; ++mb) {
#pragma unroll
    for (int r = 0; r < 4; ++r) {
      int d = dh + mb * 16 + quad * 4 + r;
      size_t off = ((size_t)b * CCH + d) * NSP + n;
      out[off] = (acc[mb][r] + bp[d] + x[off]) * RSQRT2;
    }
  }
}

extern "C" void kernel_launch(void* const* d_in, const int* in_sizes, int n_in,
                              void* d_out, int out_size, void* d_ws, size_t ws_size,
                              hipStream_t stream) {
  const float* x  = (const float*)d_in[0];
  const float* gw = (const float*)d_in[1];
  const float* gb = (const float*)d_in[2];
  const float* Wq = (const float*)d_in[3];
  const float* bq = (const float*)d_in[4];
  const float* Wk = (const float*)d_in[5];
  const float* bk = (const float*)d_in[6];
  const float* Wv = (const float*)d_in[7];
  const float* bv = (const float*)d_in[8];
  const float* Wp = (const float*)d_in[9];
  const float* bp = (const float*)d_in[10];
  float* out = (float*)d_out;

  const size_t SZ = (size_t)BB * CCH * NSP;  // 4.19M elems
  short* qb  = (short*)d_ws;                 // bf16 [b][n][c] swizzled, scaled
  short* kb  = qb + SZ;                      // bf16 [b][n][c] swizzled
  short* vb  = kb + SZ;                      // bf16 [b][c][n] permuted
  short* poT = vb + SZ;                      // bf16 [KSPLIT][b][n][c] normalized
  float* pm  = (float*)(poT + (size_t)KSPLIT * SZ);  // [KSPLIT][b][n]
  float* pl  = pm + (size_t)KSPLIT * BB * NSP;
  float* stats = pl + (size_t)KSPLIT * BB * NSP;     // [b][32][2]
  short* wts = (short*)(stats + BB * 64);            // bf16 [4][256][256]
  short* wqt = wts;
  short* wkt = wts + (size_t)CCH * CCH;
  short* wvt = wts + (size_t)2 * CCH * CCH;
  short* wpt = wts + (size_t)3 * CCH * CCH;

  gn_stats<<<dim3(BB * 32), dim3(256), 0, stream>>>(x, stats);
  prep_w<<<dim3(4, 4, 4), dim3(256), 0, stream>>>(Wq, Wk, Wv, Wp, wts);
  qkvg_kernel<<<dim3(256), dim3(512), 0, stream>>>(
      x, stats, gw, gb, wqt, wkt, wvt, bq, bk, bv, qb, kb, vb);
  attn_kernel<<<dim3(BB * 64 * KSPLIT), dim3(256), 0, stream>>>(
      qb, kb, vb, poT, pm, pl);
  proj_kernel<<<dim3(64, 2, BB), dim3(256), 0, stream>>>(
      poT, pm, pl, wpt, bp, x, out);
}

// Round 9
// 267.534 us; speedup vs baseline: 1.1912x; 1.0586x over previous
//
#include <hip/hip_runtime.h>
#include <math.h>

// AttnBlock: GroupNorm(32) -> q,k,v 1x1 -> spatial attention -> proj -> resid.
// Round 18: consolidation + launch-overhead attack.
// - attn: reverted to the R13/round-4 structure (best measured: 99.2us):
//   8 waves x 16 q/wave, K/V double-buffered (128KB), ONE barrier/tile,
//   QK(t+1) overlapped with softmax(t)+PV(t), K-DMA(t+2)/V-DMA(t+1),
//   permuted-V full-rate PV, T13 defer-rescale, cvt_pk packing, setprio.
//   (R14-17 variants: XCD swizzle flat, 32q/wave spills or 1-wave/SIMD,
//   independent 2-block = LDS-port contention — all ledgered, all reverted.)
// - gn_stats + prep_w merged into ONE prep_all launch (5 -> 4 kernels);
//   GN stats split into 2 partials/group (256 blocks, better CU fill),
//   combined in qkvg's stat load.

#define BB 4
#define CCH 256
#define NSP 4096
#define EPSV 1e-5f
#define ATTN_SCALE 0.0625f  // 256^-0.5
#define RSQRT2 0.70710678118654752440f
#define KSPLIT 2
#define TILES_PER_PART 32   // 4096 / 64 / KSPLIT

typedef __attribute__((ext_vector_type(8))) short bf16x8;
typedef __attribute__((ext_vector_type(4))) float f32x4;

typedef __attribute__((address_space(1))) void gvoid;
typedef __attribute__((address_space(3))) void lvoid;
__device__ __forceinline__ void dma16(const void* g, void* l) {
  __builtin_amdgcn_global_load_lds((gvoid*)g, (lvoid*)l, 16, 0, 0);
}

__device__ __forceinline__ short f2bf(float f) {
  union { float f; unsigned u; } a; a.f = f;
  unsigned r = a.u + 0x7fffu + ((a.u >> 16) & 1u);  // RTN-even
  return (short)(r >> 16);
}
__device__ __forceinline__ float bf2f(short s) {
  union { unsigned u; float f; } a;
  a.u = ((unsigned)(unsigned short)s) << 16;
  return a.f;
}
__device__ __forceinline__ unsigned cvt_pk_bf16(float lo, float hi) {
  unsigned r;
  asm("v_cvt_pk_bf16_f32 %0, %1, %2" : "=v"(r) : "v"(lo), "v"(hi));
  return r;
}

// ---- prep_all: GN partial stats (blocks 0..255) + W transpose (256..319) ---
// GN: block = (b,g,h): raw partial sums over channels g*8+h*4 .. +4.
//   stats[((b*32+g)*2+h)*2 + {0,1}] = {sum, sumsq}  (combined in qkvg)
// W: blocks 256..319 = original (4,4,4) prep_w grid flattened.
__global__ __launch_bounds__(256) void prep_all(
    const float* __restrict__ x,
    const float* __restrict__ Wq, const float* __restrict__ Wk,
    const float* __restrict__ Wv, const float* __restrict__ Wp,
    float* __restrict__ stats, short* __restrict__ wts) {
  __shared__ float T[64][65];
  int bid = blockIdx.x;
  int tid = threadIdx.x;
  if (bid < 256) {
    int b = bid >> 6, g = (bid >> 1) & 31, h = bid & 1;
    size_t base = ((size_t)b * CCH + (size_t)g * 8 + (size_t)h * 4) * NSP;
    const float4* xv = (const float4*)(x + base);
    float s = 0.f, ss = 0.f;
    for (int i = tid; i < 4096; i += 256) {
      float4 v = xv[i];
      s += (v.x + v.y) + (v.z + v.w);
      ss += (v.x * v.x + v.y * v.y) + (v.z * v.z + v.w * v.w);
    }
#pragma unroll
    for (int off = 32; off > 0; off >>= 1) {
      s += __shfl_down(s, off, 64);
      ss += __shfl_down(ss, off, 64);
    }
    int wv = tid >> 6;
    if ((tid & 63) == 0) { T[0][wv] = s; T[0][4 + wv] = ss; }
    __syncthreads();
    if (tid == 0) {
      float S = T[0][0] + T[0][1] + T[0][2] + T[0][3];
      float SS = T[0][4] + T[0][5] + T[0][6] + T[0][7];
      stats[((b * 32 + g) * 2 + h) * 2 + 0] = S;
      stats[((b * 32 + g) * 2 + h) * 2 + 1] = SS;
    }
  } else {
    int wid = bid - 256;
    int c0 = (wid & 3) * 64, d0 = ((wid >> 2) & 3) * 64;
    int wz = wid >> 4;
    const float* W = (wz == 0) ? Wq : (wz == 1) ? Wk : (wz == 2) ? Wv : Wp;
    short* wt = wts + (size_t)wz * CCH * CCH;
#pragma unroll
    for (int i = 0; i < 16; ++i) {
      int idx = tid + 256 * i;
      int row = idx >> 6, col = idx & 63;
      T[row][col] = W[(size_t)(c0 + row) * CCH + d0 + col];
    }
    __syncthreads();
#pragma unroll
    for (int i = 0; i < 16; ++i) {
      int idx = tid + 256 * i;
      int dr = idx >> 6, cc = idx & 63;
      wt[(size_t)(d0 + dr) * CCH + c0 + cc] = f2bf(T[cc][dr]);
    }
  }
}

// ------- qkvg: fused GN-apply + q,k,v projections via bf16 MFMA -----------
// 512 threads / 8 waves: wave w handles rows (w&3)*16.. and d-half (w>>2).
// q/k outputs chunk-swizzled for linear DMA into attn's LDS. v output [c][n]
// stores, within each 64-key tile, key mm at permuted position
// pk = ((mb&1)<<5)|(q<<3)|((mb>>1)<<2)|r, then bank-swizzled by (c&7).
__global__ __launch_bounds__(512) void qkvg_kernel(
    const float* __restrict__ x, const float* __restrict__ stats,
    const float* __restrict__ gw, const float* __restrict__ gb,
    const short* __restrict__ wqt, const short* __restrict__ wkt,
    const short* __restrict__ wvt,
    const float* __restrict__ bq, const float* __restrict__ bk,
    const float* __restrict__ bv,
    short* __restrict__ qo, short* __restrict__ ko, short* __restrict__ vo) {
  __shared__ __align__(16) unsigned char smem[52224];
  float (*Ts)[68] = (float(*)[68])smem;          // 64 x 68 fp32 (17408 B)
  float* aco = (float*)(smem + 17408);           // 256 f32
  float* bco = aco + 256;                        // 256 f32
  short* Hs = (short*)(smem + 19456);            // [64 n][256 c] swizzled bf16
  short* Fo = (short*)smem;                      // epilogue [64 n][264] bf16

  int bx = blockIdx.x;
  int b = bx & 3, n0 = (bx >> 2) * 64;
  int tid = threadIdx.x;
  if (tid < 256) {  // per-channel scale/shift (combine 2 GN partials)
    int g = tid >> 3;
    const float* sp = stats + (size_t)(b * 32 + g) * 4;
    float S = sp[0] + sp[2], SS = sp[1] + sp[3];
    float mean = S * (1.f / 32768.f);
    float var = SS * (1.f / 32768.f) - mean * mean;
    float rstd = rsqrtf(var + EPSV);
    float a = gw[tid] * rstd;
    aco[tid] = a;
    bco[tid] = gb[tid] - mean * a;
  }
  __syncthreads();
  const float* xb = x + (size_t)b * CCH * NSP;
  // ---- 4 passes: load x chunk, normalize, transpose, bf16 -> swizzled Hs --
  for (int p = 0; p < 4; ++p) {
    int c0 = p * 64;
#pragma unroll
    for (int i = 0; i < 2; ++i) {
      int crow = (tid >> 4) + i * 32;
      int c = c0 + crow;
      float4 v = *(const float4*)&xb[(size_t)c * NSP + n0 + (tid & 15) * 4];
      float a = aco[c], bb = bco[c];
      v.x = v.x * a + bb; v.y = v.y * a + bb;
      v.z = v.z * a + bb; v.w = v.w * a + bb;
      *(float4*)&Ts[crow][(tid & 15) * 4] = v;   // Ts[c_local][n_local]
    }
    __syncthreads();
    {
      int n = tid >> 3, seg = tid & 7;
      int cb = seg * 8;
      bf16x8 r;
#pragma unroll
      for (int j = 0; j < 8; ++j) r[j] = f2bf(Ts[cb + j][n]);
      int chunk = (c0 + cb) >> 3;
      *(bf16x8*)(Hs + n * 256 + ((chunk ^ (n & 7)) * 8)) = r;
    }
    __syncthreads();
  }
  // ---- extract B-frags (rows = this wave's 16 n) ----
  int w = tid >> 6, lane = tid & 63, quad = lane >> 4, l16 = lane & 15;
  int wr = w & 3, h = w >> 2;  // row-group, d-half
  bf16x8 a_h[8];
  {
    int row = wr * 16 + l16;
#pragma unroll
    for (int kc = 0; kc < 8; ++kc)
      a_h[kc] = *(bf16x8*)(Hs + row * 256 + (((kc * 4 + quad) ^ (row & 7)) * 8));
  }
  __syncthreads();  // all waves extracted; smem reusable as Fo
  // ---- 3 projections; wave handles d in [h*128, h*128+128) ----
  for (int op = 0; op < 3; ++op) {
    const short* wt = (op == 0) ? wqt : (op == 1) ? wkt : wvt;
    const float* bias = (op == 0) ? bq : (op == 1) ? bk : bv;
    f32x4 acc[8];
#pragma unroll
    for (int mb = 0; mb < 8; ++mb) acc[mb] = (f32x4){0.f, 0.f, 0.f, 0.f};
#pragma unroll 4
    for (int mb = 0; mb < 8; ++mb) {
      const short* wp = wt + (size_t)((h * 8 + mb) * 16 + l16) * CCH + quad * 8;
#pragma unroll
      for (int kc = 0; kc < 8; ++kc) {
        bf16x8 af = *(const bf16x8*)(wp + kc * 32);
        acc[mb] = __builtin_amdgcn_mfma_f32_16x16x32_bf16(af, a_h[kc], acc[mb], 0, 0, 0);
      }
    }
    int n = n0 + wr * 16 + l16;
    if (op == 2) {  // v: [c][n-permuted] scalar stores
      short* ob = vo + (size_t)b * CCH * NSP;
      int mm = n & 63, m0_ = n & ~63;
      int mb_ = mm >> 4, qq = (mm >> 2) & 3, rr2 = mm & 3;
      int lc = (mb_ & 1) * 4 + qq;          // logical 8-key chunk
      int jj = (mb_ >> 1) * 4 + rr2;        // slot within chunk
      int basen = m0_ + jj;
#pragma unroll
      for (int mb = 0; mb < 8; ++mb)
#pragma unroll
        for (int r = 0; r < 4; ++r) {
          int d = (h * 8 + mb) * 16 + quad * 4 + r;
          ob[(size_t)d * NSP + basen + ((lc ^ (d & 7)) << 3)] =
              f2bf(acc[mb][r] + bias[d]);
        }
    } else {  // q/k: transpose via Fo -> [n][c] b128 stores, chunk-swizzled
      float sc = (op == 0) ? ATTN_SCALE : 1.f;
      int nl = wr * 16 + l16;
#pragma unroll
      for (int mb = 0; mb < 8; ++mb)
#pragma unroll
        for (int r = 0; r < 4; ++r) {
          int d = (h * 8 + mb) * 16 + quad * 4 + r;
          Fo[nl * 264 + d] = f2bf((acc[mb][r] + bias[d]) * sc);
        }
      __syncthreads();
      short* ob = ((op == 0) ? qo : ko) + (size_t)b * NSP * CCH;
      {
        int row = tid >> 3, seg = tid & 7, r7 = row & 7;
        short* dst = ob + (size_t)(n0 + row) * CCH + seg * 32;
#pragma unroll
        for (int i = 0; i < 4; ++i) {
          int xch = seg * 4 + i;
          int cs = (xch & 24) | ((xch & 7) ^ r7);  // source chunk for slot xch
          *(bf16x8*)(dst + i * 8) = *(bf16x8*)(Fo + row * 264 + cs * 8);
        }
      }
      __syncthreads();
    }
  }
}

// ------ flash attention: 8 waves, 16 q/wave, 128 q/block, pipelined --------
// R13/round-4 structure (best measured). K,V double-buffered (128 KiB LDS);
// one barrier per tile; QK(t+1) overlaps softmax(t)+PV(t).
__global__ __launch_bounds__(512, 1) void attn_kernel(
    const short* __restrict__ q, const short* __restrict__ k,
    const short* __restrict__ v, short* __restrict__ po,
    float* __restrict__ pm, float* __restrict__ pl) {
  __shared__ __align__(16) unsigned char smem[131072];  // 128 KB
  short* Ks0 = (short*)smem;             // K even tiles / Q stage
  short* Ks1 = (short*)(smem + 32768);   // K odd tiles
  short* Vs0 = (short*)(smem + 65536);   // V even tiles
  short* Vs1 = (short*)(smem + 98304);   // V odd tiles
  short* Fo  = (short*)smem;             // epilogue [64 n][264 c] bf16

  int bx = blockIdx.x;
  int b = bx & 3;
  int n0 = ((bx >> 2) & 31) << 7;   // 128-query block
  int kh = bx >> 7;                 // key half
  const short* qb = q + (size_t)b * NSP * CCH;
  const short* kb = k + (size_t)b * NSP * CCH;
  const char*  vbB = (const char*)(v + (size_t)b * CCH * NSP);
  int tid = threadIdx.x;
  int w = tid >> 6, lane = tid & 63, quad = lane >> 4, l16 = lane & 15;
  int mbase = kh * TILES_PER_PART * 64;

  // ---- stage Q in 2 passes of 64 rows through Ks0; extract B-frags ----
  bf16x8 a_q[8];
#pragma unroll
  for (int p = 0; p < 2; ++p) {
#pragma unroll
    for (int i = 0; i < 4; ++i) {
      int off = tid * 16 + i * 8192;
      dma16((const char*)(qb + (size_t)(n0 + p * 64) * CCH) + off,
            (char*)Ks0 + off);
    }
    __syncthreads();
    if ((w >> 2) == p) {
      int row = (w & 3) * 16 + l16;
#pragma unroll
      for (int kc = 0; kc < 8; ++kc)
        a_q[kc] = *(bf16x8*)(Ks0 + row * 256 + (((kc * 4 + quad) ^ (row & 7)) * 8));
    }
    __syncthreads();
  }

  // ---- prologue: K0->Ks0, V0->Vs0; drain; K1->Ks1; QK(0) ----
#pragma unroll
  for (int i = 0; i < 4; ++i) {
    int off = tid * 16 + i * 8192;
    dma16((const char*)(kb + (size_t)mbase * CCH) + off, (char*)Ks0 + off);
    int c = off >> 7, inrow = off & 127;
    dma16(vbB + (size_t)c * (NSP * 2) + (size_t)mbase * 2 + inrow,
          (char*)Vs0 + off);
  }
  __syncthreads();
#pragma unroll
  for (int i = 0; i < 4; ++i) {
    int off = tid * 16 + i * 8192;
    dma16((const char*)(kb + (size_t)(mbase + 64) * CCH) + off,
          (char*)Ks1 + off);
  }
  f32x4 s_prev[4];
#pragma unroll
  for (int mb = 0; mb < 4; ++mb) s_prev[mb] = (f32x4){0.f, 0.f, 0.f, 0.f};
  __builtin_amdgcn_s_setprio(1);
#pragma unroll
  for (int kc = 0; kc < 8; ++kc) {
#pragma unroll
    for (int mb = 0; mb < 4; ++mb) {
      int row = mb * 16 + l16;
      bf16x8 kf = *(bf16x8*)(Ks0 + row * 256 + (((kc * 4 + quad) ^ (row & 7)) * 8));
      s_prev[mb] = __builtin_amdgcn_mfma_f32_16x16x32_bf16(kf, a_q[kc], s_prev[mb], 0, 0, 0);
    }
  }
  __builtin_amdgcn_s_setprio(0);

  f32x4 accO[16];  // O^T C-layout: ch = cb*16 + quad*4 + r, query = w*16+l16
#pragma unroll
  for (int cb = 0; cb < 16; ++cb) accO[cb] = (f32x4){0.f, 0.f, 0.f, 0.f};
  float m_run = -1e30f, l_run = 0.f;
  int pc0 = quad ^ (l16 & 7);        // V chunk for key-group 0 (loop-invariant)
  int pc1 = (4 + quad) ^ (l16 & 7);  // key-group 1

#pragma unroll 1
  for (int t = 0; t < TILES_PER_PART; ++t) {
    __syncthreads();  // DMA(issued last iter) complete; buffers' readers done
    short* Kd = (t & 1) ? Ks1 : Ks0;   // dest for K(t+2)
    short* Kr = (t & 1) ? Ks0 : Ks1;   // source for QK(t+1)
    short* Vd = (t & 1) ? Vs0 : Vs1;   // dest for V(t+1)
    short* Vr = (t & 1) ? Vs1 : Vs0;   // source for PV(t)
    if (t + 2 < TILES_PER_PART) {      // K-DMA(t+2): last read by QK(t) prev iter
      const char* kp = (const char*)(kb + (size_t)(mbase + (t + 2) * 64) * CCH);
#pragma unroll
      for (int i = 0; i < 4; ++i) {
        int off = tid * 16 + i * 8192;
        dma16(kp + off, (char*)Kd + off);
      }
    }
    if (t + 1 < TILES_PER_PART) {      // V-DMA(t+1): last read by PV(t-1)
      int m0 = mbase + (t + 1) * 64;
#pragma unroll
      for (int i = 0; i < 4; ++i) {
        int off = tid * 16 + i * 8192;
        int c = off >> 7, inrow = off & 127;
        dma16(vbB + (size_t)c * (NSP * 2) + (size_t)m0 * 2 + inrow,
              (char*)Vd + off);
      }
    }
    // ---- QK(t+1): independent MFMA stream, fills pipe under softmax(t) ----
    f32x4 sn[4];
#pragma unroll
    for (int mb = 0; mb < 4; ++mb) sn[mb] = (f32x4){0.f, 0.f, 0.f, 0.f};
    if (t + 1 < TILES_PER_PART) {
      __builtin_amdgcn_s_setprio(1);
#pragma unroll
      for (int kc = 0; kc < 8; ++kc) {
#pragma unroll
        for (int mb = 0; mb < 4; ++mb) {
          int row = mb * 16 + l16;
          bf16x8 kf = *(bf16x8*)(Kr + row * 256 + (((kc * 4 + quad) ^ (row & 7)) * 8));
          sn[mb] = __builtin_amdgcn_mfma_f32_16x16x32_bf16(kf, a_q[kc], sn[mb], 0, 0, 0);
        }
      }
      __builtin_amdgcn_s_setprio(0);
    }
    // ---- online softmax(t) on s_prev: per-lane scalar stats ----
    float mx = -1e30f;
#pragma unroll
    for (int mb = 0; mb < 4; ++mb)
#pragma unroll
      for (int r = 0; r < 4; ++r) mx = fmaxf(mx, s_prev[mb][r]);
    mx = fmaxf(mx, __shfl_xor(mx, 16));
    mx = fmaxf(mx, __shfl_xor(mx, 32));
    if (!__all(mx - m_run <= 8.f)) {   // T13: rescale only when max grows >8
      float mnew = fmaxf(m_run, mx);
      float alpha = __expf(m_run - mnew);
#pragma unroll
      for (int cb = 0; cb < 16; ++cb) accO[cb] *= alpha;
      l_run *= alpha;
      m_run = mnew;
    }
    float ls = 0.f;
#pragma unroll
    for (int mb = 0; mb < 4; ++mb)
#pragma unroll
      for (int r = 0; r < 4; ++r) {
        float p = __expf(s_prev[mb][r] - m_run);   // bounded by e^8
        ls += p;
        s_prev[mb][r] = p;
      }
    ls += __shfl_xor(ls, 16);
    ls += __shfl_xor(ls, 32);
    l_run += ls;
    // ---- pack P into 16x16x32 B-frags (key permutation makes this direct) --
    union { unsigned u[4]; bf16x8 v; } pw0, pw1;
    pw0.u[0] = cvt_pk_bf16(s_prev[0][0], s_prev[0][1]);
    pw0.u[1] = cvt_pk_bf16(s_prev[0][2], s_prev[0][3]);
    pw0.u[2] = cvt_pk_bf16(s_prev[2][0], s_prev[2][1]);
    pw0.u[3] = cvt_pk_bf16(s_prev[2][2], s_prev[2][3]);
    pw1.u[0] = cvt_pk_bf16(s_prev[1][0], s_prev[1][1]);
    pw1.u[1] = cvt_pk_bf16(s_prev[1][2], s_prev[1][3]);
    pw1.u[2] = cvt_pk_bf16(s_prev[3][0], s_prev[3][1]);
    pw1.u[3] = cvt_pk_bf16(s_prev[3][2], s_prev[3][3]);
    // ---- O^T += V P^T : full-rate 16x16x32, b128 V reads ----
    __builtin_amdgcn_s_setprio(1);
#pragma unroll
    for (int cb = 0; cb < 16; ++cb) {
      bf16x8 vf = *(bf16x8*)(Vr + (cb * 16 + l16) * 64 + pc0 * 8);
      accO[cb] = __builtin_amdgcn_mfma_f32_16x16x32_bf16(vf, pw0.v, accO[cb], 0, 0, 0);
    }
#pragma unroll
    for (int cb = 0; cb < 16; ++cb) {
      bf16x8 vf = *(bf16x8*)(Vr + (cb * 16 + l16) * 64 + pc1 * 8);
      accO[cb] = __builtin_amdgcn_mfma_f32_16x16x32_bf16(vf, pw1.v, accO[cb], 0, 0, 0);
    }
    __builtin_amdgcn_s_setprio(0);
    // ---- roll S ----
#pragma unroll
    for (int mb = 0; mb < 4; ++mb) s_prev[mb] = sn[mb];
  }
  // ---- stats ----
  size_t sbase = ((size_t)kh * BB + b) * NSP + n0;
  if (quad == 0) {
    pm[sbase + w * 16 + l16] = m_run;
    pl[sbase + w * 16 + l16] = l_run;
  }
  // ---- epilogue: normalized bf16 O -> po [kh][b][n][c], LDS transpose ----
  float linv = 1.f / l_run;
  short* ob = po + ((size_t)kh * BB + b) * NSP * CCH;
#pragma unroll
  for (int p = 0; p < 2; ++p) {
    __syncthreads();
    if ((w >> 2) == p) {
      int nloc = (w & 3) * 16 + l16;
#pragma unroll
      for (int cb = 0; cb < 16; ++cb)
#pragma unroll
        for (int r = 0; r < 4; ++r)
          Fo[nloc * 264 + cb * 16 + quad * 4 + r] = f2bf(accO[cb][r] * linv);
    }
    __syncthreads();
    int row = tid >> 3, seg = tid & 7;
    short* dst = ob + (size_t)(n0 + p * 64 + row) * CCH + seg * 32;
#pragma unroll
    for (int i = 0; i < 4; ++i)
      *(bf16x8*)(dst + i * 8) = *(bf16x8*)(Fo + row * 264 + seg * 32 + i * 8);
  }
}

// ------- proj: frag-direct MFMA, KSPLIT-way merge in registers, +bias+resid -
__global__ __launch_bounds__(256) void proj_kernel(
    const short* __restrict__ po, const float* __restrict__ pm,
    const float* __restrict__ pl, const short* __restrict__ wpt,
    const float* __restrict__ bp, const float* __restrict__ x,
    float* __restrict__ out) {
  int n0 = blockIdx.x * 64;
  int dh = blockIdx.y * 128;
  int b = blockIdx.z;
  int tid = threadIdx.x;
  int w = tid >> 6, lane = tid & 63, quad = lane >> 4, l16 = lane & 15;
  int n = n0 + w * 16 + l16;

  float wgt[KSPLIT];
  {
    float m[KSPLIT];
    float M = -1e30f;
#pragma unroll
    for (int s = 0; s < KSPLIT; ++s) {
      m[s] = pm[((size_t)s * BB + b) * NSP + n];
      M = fmaxf(M, m[s]);
    }
    float wsum = 0.f;
#pragma unroll
    for (int s = 0; s < KSPLIT; ++s) {
      wgt[s] = __expf(m[s] - M) * pl[((size_t)s * BB + b) * NSP + n];
      wsum += wgt[s];
    }
    float linv = 1.f / wsum;
#pragma unroll
    for (int s = 0; s < KSPLIT; ++s) wgt[s] *= linv;
  }

  f32x4 acc[8];
#pragma unroll
  for (int mb = 0; mb < 8; ++mb) acc[mb] = (f32x4){0.f, 0.f, 0.f, 0.f};

  const short* pob = po + ((size_t)b * NSP + n) * CCH;
#pragma unroll 2
  for (int kc = 0; kc < 8; ++kc) {
    int coff = kc * 32 + quad * 8;
    float e[8];
#pragma unroll
    for (int i = 0; i < 8; ++i) e[i] = 0.f;
#pragma unroll
    for (int s = 0; s < KSPLIT; ++s) {
      bf16x8 f = *(const bf16x8*)(pob + (size_t)s * BB * NSP * CCH + coff);
#pragma unroll
      for (int i = 0; i < 8; ++i) e[i] += wgt[s] * bf2f(f[i]);
    }
    bf16x8 bm;
#pragma unroll
    for (int i = 0; i < 8; ++i) bm[i] = f2bf(e[i]);
#pragma unroll
    for (int mb = 0; mb < 8; ++mb) {
      bf16x8 af = *(const bf16x8*)(wpt + (size_t)(dh + mb * 16 + l16) * CCH + coff);
      acc[mb] = __builtin_amdgcn_mfma_f32_16x16x32_bf16(af, bm, acc[mb], 0, 0, 0);
    }
  }
#pragma unroll
  for (int mb = 0; mb < 8; ++mb) {
#pragma unroll
    for (int r = 0; r < 4; ++r) {
      int d = dh + mb * 16 + quad * 4 + r;
      size_t off = ((size_t)b * CCH + d) * NSP + n;
      out[off] = (acc[mb][r] + bp[d] + x[off]) * RSQRT2;
    }
  }
}

extern "C" void kernel_launch(void* const* d_in, const int* in_sizes, int n_in,
                              void* d_out, int out_size, void* d_ws, size_t ws_size,
                              hipStream_t stream) {
  const float* x  = (const float*)d_in[0];
  const float* gw = (const float*)d_in[1];
  const float* gb = (const float*)d_in[2];
  const float* Wq = (const float*)d_in[3];
  const float* bq = (const float*)d_in[4];
  const float* Wk = (const float*)d_in[5];
  const float* bk = (const float*)d_in[6];
  const float* Wv = (const float*)d_in[7];
  const float* bv = (const float*)d_in[8];
  const float* Wp = (const float*)d_in[9];
  const float* bp = (const float*)d_in[10];
  float* out = (float*)d_out;

  const size_t SZ = (size_t)BB * CCH * NSP;  // 4.19M elems
  short* qb  = (short*)d_ws;                 // bf16 [b][n][c] swizzled, scaled
  short* kb  = qb + SZ;                      // bf16 [b][n][c] swizzled
  short* vb  = kb + SZ;                      // bf16 [b][c][n] permuted
  short* poT = vb + SZ;                      // bf16 [KSPLIT][b][n][c] normalized
  float* pm  = (float*)(poT + (size_t)KSPLIT * SZ);  // [KSPLIT][b][n]
  float* pl  = pm + (size_t)KSPLIT * BB * NSP;
  float* stats = pl + (size_t)KSPLIT * BB * NSP;     // [b][32][2 half][2] raw
  short* wts = (short*)(stats + BB * 128);           // bf16 [4][256][256]
  short* wqt = wts;
  short* wkt = wts + (size_t)CCH * CCH;
  short* wvt = wts + (size_t)2 * CCH * CCH;
  short* wpt = wts + (size_t)3 * CCH * CCH;

  prep_all<<<dim3(320), dim3(256), 0, stream>>>(x, Wq, Wk, Wv, Wp, stats, wts);
  qkvg_kernel<<<dim3(256), dim3(512), 0, stream>>>(
      x, stats, gw, gb, wqt, wkt, wvt, bq, bk, bv, qb, kb, vb);
  attn_kernel<<<dim3(BB * 32 * KSPLIT), dim3(512), 0, stream>>>(
      qb, kb, vb, poT, pm, pl);
  proj_kernel<<<dim3(64, 2, BB), dim3(256), 0, stream>>>(
      poT, pm, pl, wpt, bp, x, out);
}

// Round 10
// 265.627 us; speedup vs baseline: 1.1997x; 1.0072x over previous
//
#include <hip/hip_runtime.h>
#include <math.h>

// AttnBlock: GroupNorm(32) -> q,k,v 1x1 -> spatial attention -> proj -> resid.
// Round 19: TLP for the non-attn kernels (168.7us, ~3x above their memory
// floors -> latency-bound serial phases). qkvg: n-block 64->32, 512 blocks =
// 2 independent blocks/CU (weight-L2 traffic unchanged: redundancy halves as
// blocks double); 256 thr / 4 waves (2 wr x 2 h). proj: n-block 64->32, 1024
// blocks = 4 blocks/CU, waves = 2 n-groups x 2 d-quarters. attn + prep_all
// unchanged (R9-proven: attn 98.8us, 8-wave pipelined structure).

#define BB 4
#define CCH 256
#define NSP 4096
#define EPSV 1e-5f
#define ATTN_SCALE 0.0625f  // 256^-0.5
#define RSQRT2 0.70710678118654752440f
#define KSPLIT 2
#define TILES_PER_PART 32   // 4096 / 64 / KSPLIT

typedef __attribute__((ext_vector_type(8))) short bf16x8;
typedef __attribute__((ext_vector_type(4))) float f32x4;

typedef __attribute__((address_space(1))) void gvoid;
typedef __attribute__((address_space(3))) void lvoid;
__device__ __forceinline__ void dma16(const void* g, void* l) {
  __builtin_amdgcn_global_load_lds((gvoid*)g, (lvoid*)l, 16, 0, 0);
}

__device__ __forceinline__ short f2bf(float f) {
  union { float f; unsigned u; } a; a.f = f;
  unsigned r = a.u + 0x7fffu + ((a.u >> 16) & 1u);  // RTN-even
  return (short)(r >> 16);
}
__device__ __forceinline__ float bf2f(short s) {
  union { unsigned u; float f; } a;
  a.u = ((unsigned)(unsigned short)s) << 16;
  return a.f;
}
__device__ __forceinline__ unsigned cvt_pk_bf16(float lo, float hi) {
  unsigned r;
  asm("v_cvt_pk_bf16_f32 %0, %1, %2" : "=v"(r) : "v"(lo), "v"(hi));
  return r;
}

// ---- prep_all: GN partial stats (blocks 0..255) + W transpose (256..319) ---
__global__ __launch_bounds__(256) void prep_all(
    const float* __restrict__ x,
    const float* __restrict__ Wq, const float* __restrict__ Wk,
    const float* __restrict__ Wv, const float* __restrict__ Wp,
    float* __restrict__ stats, short* __restrict__ wts) {
  __shared__ float T[64][65];
  int bid = blockIdx.x;
  int tid = threadIdx.x;
  if (bid < 256) {
    int b = bid >> 6, g = (bid >> 1) & 31, h = bid & 1;
    size_t base = ((size_t)b * CCH + (size_t)g * 8 + (size_t)h * 4) * NSP;
    const float4* xv = (const float4*)(x + base);
    float s = 0.f, ss = 0.f;
    for (int i = tid; i < 4096; i += 256) {
      float4 v = xv[i];
      s += (v.x + v.y) + (v.z + v.w);
      ss += (v.x * v.x + v.y * v.y) + (v.z * v.z + v.w * v.w);
    }
#pragma unroll
    for (int off = 32; off > 0; off >>= 1) {
      s += __shfl_down(s, off, 64);
      ss += __shfl_down(ss, off, 64);
    }
    int wv = tid >> 6;
    if ((tid & 63) == 0) { T[0][wv] = s; T[0][4 + wv] = ss; }
    __syncthreads();
    if (tid == 0) {
      float S = T[0][0] + T[0][1] + T[0][2] + T[0][3];
      float SS = T[0][4] + T[0][5] + T[0][6] + T[0][7];
      stats[((b * 32 + g) * 2 + h) * 2 + 0] = S;
      stats[((b * 32 + g) * 2 + h) * 2 + 1] = SS;
    }
  } else {
    int wid = bid - 256;
    int c0 = (wid & 3) * 64, d0 = ((wid >> 2) & 3) * 64;
    int wz = wid >> 4;
    const float* W = (wz == 0) ? Wq : (wz == 1) ? Wk : (wz == 2) ? Wv : Wp;
    short* wt = wts + (size_t)wz * CCH * CCH;
#pragma unroll
    for (int i = 0; i < 16; ++i) {
      int idx = tid + 256 * i;
      int row = idx >> 6, col = idx & 63;
      T[row][col] = W[(size_t)(c0 + row) * CCH + d0 + col];
    }
    __syncthreads();
#pragma unroll
    for (int i = 0; i < 16; ++i) {
      int idx = tid + 256 * i;
      int dr = idx >> 6, cc = idx & 63;
      wt[(size_t)(d0 + dr) * CCH + c0 + cc] = f2bf(T[cc][dr]);
    }
  }
}

// ------- qkvg: fused GN-apply + q,k,v projections via bf16 MFMA -----------
// n-block = 32, grid 512 = 2 independent blocks/CU. 256 threads / 4 waves:
// wave w: wr = w&1 (n-group of 16), h = w>>1 (d-half of 128).
// q/k outputs chunk-swizzled for linear DMA into attn's LDS. v output [c][n]
// key-permuted + bank-swizzled (same formulas as before, using global n).
__global__ __launch_bounds__(256) void qkvg_kernel(
    const float* __restrict__ x, const float* __restrict__ stats,
    const float* __restrict__ gw, const float* __restrict__ gb,
    const short* __restrict__ wqt, const short* __restrict__ wkt,
    const short* __restrict__ wvt,
    const float* __restrict__ bq, const float* __restrict__ bk,
    const float* __restrict__ bv,
    short* __restrict__ qo, short* __restrict__ ko, short* __restrict__ vo) {
  __shared__ __align__(16) unsigned char smem[26880];
  float* aco = (float*)smem;                      // 256 f32
  float* bco = aco + 256;                         // 256 f32
  float (*Ts)[33] = (float(*)[33])(smem + 2048);  // 64 x 33 fp32 (8448 B)
  short* Hs = (short*)(smem + 10496);             // [32 n][256 c] swizzled
  short* Fo = (short*)(smem + 2048);              // epilogue [32 n][264] bf16

  int bx = blockIdx.x;
  int b = bx & 3, n0 = (bx >> 2) * 32;
  int tid = threadIdx.x;
  {  // per-channel scale/shift (combine 2 GN partials)
    int g = tid >> 3;
    const float* sp = stats + (size_t)(b * 32 + g) * 4;
    float S = sp[0] + sp[2], SS = sp[1] + sp[3];
    float mean = S * (1.f / 32768.f);
    float var = SS * (1.f / 32768.f) - mean * mean;
    float rstd = rsqrtf(var + EPSV);
    float a = gw[tid] * rstd;
    aco[tid] = a;
    bco[tid] = gb[tid] - mean * a;
  }
  __syncthreads();
  const float* xb = x + (size_t)b * CCH * NSP;
  // ---- 4 passes: load x chunk (64c x 32n), normalize, transpose -> Hs ----
  for (int p = 0; p < 4; ++p) {
    int c0 = p * 64;
#pragma unroll
    for (int i = 0; i < 2; ++i) {
      int crow = (tid >> 3) + i * 32;
      int c = c0 + crow;
      float4 v = *(const float4*)&xb[(size_t)c * NSP + n0 + (tid & 7) * 4];
      float a = aco[c], bb = bco[c];
      v.x = v.x * a + bb; v.y = v.y * a + bb;
      v.z = v.z * a + bb; v.w = v.w * a + bb;
      *(float4*)&Ts[crow][(tid & 7) * 4] = v;   // Ts[c_local][n_local]
    }
    __syncthreads();
    {
      int n = tid >> 3, seg = tid & 7;
      int cb = seg * 8;
      bf16x8 r;
#pragma unroll
      for (int j = 0; j < 8; ++j) r[j] = f2bf(Ts[cb + j][n]);
      int chunk = p * 8 + seg;
      *(bf16x8*)(Hs + n * 256 + ((chunk ^ (n & 7)) * 8)) = r;
    }
    __syncthreads();
  }
  // ---- extract B-frags (rows = this wave's 16 n; shared across h) ----
  int w = tid >> 6, lane = tid & 63, quad = lane >> 4, l16 = lane & 15;
  int wr = w & 1, h = w >> 1;  // n-group, d-half
  bf16x8 a_h[8];
  {
    int row = wr * 16 + l16;
#pragma unroll
    for (int kc = 0; kc < 8; ++kc)
      a_h[kc] = *(bf16x8*)(Hs + row * 256 + (((kc * 4 + quad) ^ (row & 7)) * 8));
  }
  __syncthreads();  // all waves extracted; smem reusable as Fo
  // ---- 3 projections; wave handles d in [h*128, h*128+128) ----
  for (int op = 0; op < 3; ++op) {
    const short* wt = (op == 0) ? wqt : (op == 1) ? wkt : wvt;
    const float* bias = (op == 0) ? bq : (op == 1) ? bk : bv;
    f32x4 acc[8];
#pragma unroll
    for (int mb = 0; mb < 8; ++mb) acc[mb] = (f32x4){0.f, 0.f, 0.f, 0.f};
#pragma unroll 4
    for (int mb = 0; mb < 8; ++mb) {
      const short* wp = wt + (size_t)((h * 8 + mb) * 16 + l16) * CCH + quad * 8;
#pragma unroll
      for (int kc = 0; kc < 8; ++kc) {
        bf16x8 af = *(const bf16x8*)(wp + kc * 32);
        acc[mb] = __builtin_amdgcn_mfma_f32_16x16x32_bf16(af, a_h[kc], acc[mb], 0, 0, 0);
      }
    }
    int n = n0 + wr * 16 + l16;
    if (op == 2) {  // v: [c][n-permuted] scalar stores (global-n formulas)
      short* ob = vo + (size_t)b * CCH * NSP;
      int mm = n & 63, m0_ = n & ~63;
      int mb_ = mm >> 4, qq = (mm >> 2) & 3, rr2 = mm & 3;
      int lc = (mb_ & 1) * 4 + qq;          // logical 8-key chunk
      int jj = (mb_ >> 1) * 4 + rr2;        // slot within chunk
      int basen = m0_ + jj;
#pragma unroll
      for (int mb = 0; mb < 8; ++mb)
#pragma unroll
        for (int r = 0; r < 4; ++r) {
          int d = (h * 8 + mb) * 16 + quad * 4 + r;
          ob[(size_t)d * NSP + basen + ((lc ^ (d & 7)) << 3)] =
              f2bf(acc[mb][r] + bias[d]);
        }
    } else {  // q/k: transpose via Fo -> [n][c] b128 stores, chunk-swizzled
      float sc = (op == 0) ? ATTN_SCALE : 1.f;
      int nl = wr * 16 + l16;
#pragma unroll
      for (int mb = 0; mb < 8; ++mb)
#pragma unroll
        for (int r = 0; r < 4; ++r) {
          int d = (h * 8 + mb) * 16 + quad * 4 + r;
          Fo[nl * 264 + d] = f2bf((acc[mb][r] + bias[d]) * sc);
        }
      __syncthreads();
      short* ob = ((op == 0) ? qo : ko) + (size_t)b * NSP * CCH;
      {
        int row = tid >> 3, seg = tid & 7, r7 = row & 7;  // row 0..31
        short* dst = ob + (size_t)(n0 + row) * CCH + seg * 32;
#pragma unroll
        for (int i = 0; i < 4; ++i) {
          int xch = seg * 4 + i;
          int cs = (xch & 24) | ((xch & 7) ^ r7);  // source chunk for slot xch
          *(bf16x8*)(dst + i * 8) = *(bf16x8*)(Fo + row * 264 + cs * 8);
        }
      }
      __syncthreads();
    }
  }
}

// ------ flash attention: 8 waves, 16 q/wave, 128 q/block, pipelined --------
// R13/round-4 structure (best measured). K,V double-buffered (128 KiB LDS);
// one barrier per tile; QK(t+1) overlaps softmax(t)+PV(t).
__global__ __launch_bounds__(512, 1) void attn_kernel(
    const short* __restrict__ q, const short* __restrict__ k,
    const short* __restrict__ v, short* __restrict__ po,
    float* __restrict__ pm, float* __restrict__ pl) {
  __shared__ __align__(16) unsigned char smem[131072];  // 128 KB
  short* Ks0 = (short*)smem;             // K even tiles / Q stage
  short* Ks1 = (short*)(smem + 32768);   // K odd tiles
  short* Vs0 = (short*)(smem + 65536);   // V even tiles
  short* Vs1 = (short*)(smem + 98304);   // V odd tiles
  short* Fo  = (short*)smem;             // epilogue [64 n][264 c] bf16

  int bx = blockIdx.x;
  int b = bx & 3;
  int n0 = ((bx >> 2) & 31) << 7;   // 128-query block
  int kh = bx >> 7;                 // key half
  const short* qb = q + (size_t)b * NSP * CCH;
  const short* kb = k + (size_t)b * NSP * CCH;
  const char*  vbB = (const char*)(v + (size_t)b * CCH * NSP);
  int tid = threadIdx.x;
  int w = tid >> 6, lane = tid & 63, quad = lane >> 4, l16 = lane & 15;
  int mbase = kh * TILES_PER_PART * 64;

  // ---- stage Q in 2 passes of 64 rows through Ks0; extract B-frags ----
  bf16x8 a_q[8];
#pragma unroll
  for (int p = 0; p < 2; ++p) {
#pragma unroll
    for (int i = 0; i < 4; ++i) {
      int off = tid * 16 + i * 8192;
      dma16((const char*)(qb + (size_t)(n0 + p * 64) * CCH) + off,
            (char*)Ks0 + off);
    }
    __syncthreads();
    if ((w >> 2) == p) {
      int row = (w & 3) * 16 + l16;
#pragma unroll
      for (int kc = 0; kc < 8; ++kc)
        a_q[kc] = *(bf16x8*)(Ks0 + row * 256 + (((kc * 4 + quad) ^ (row & 7)) * 8));
    }
    __syncthreads();
  }

  // ---- prologue: K0->Ks0, V0->Vs0; drain; K1->Ks1; QK(0) ----
#pragma unroll
  for (int i = 0; i < 4; ++i) {
    int off = tid * 16 + i * 8192;
    dma16((const char*)(kb + (size_t)mbase * CCH) + off, (char*)Ks0 + off);
    int c = off >> 7, inrow = off & 127;
    dma16(vbB + (size_t)c * (NSP * 2) + (size_t)mbase * 2 + inrow,
          (char*)Vs0 + off);
  }
  __syncthreads();
#pragma unroll
  for (int i = 0; i < 4; ++i) {
    int off = tid * 16 + i * 8192;
    dma16((const char*)(kb + (size_t)(mbase + 64) * CCH) + off,
          (char*)Ks1 + off);
  }
  f32x4 s_prev[4];
#pragma unroll
  for (int mb = 0; mb < 4; ++mb) s_prev[mb] = (f32x4){0.f, 0.f, 0.f, 0.f};
  __builtin_amdgcn_s_setprio(1);
#pragma unroll
  for (int kc = 0; kc < 8; ++kc) {
#pragma unroll
    for (int mb = 0; mb < 4; ++mb) {
      int row = mb * 16 + l16;
      bf16x8 kf = *(bf16x8*)(Ks0 + row * 256 + (((kc * 4 + quad) ^ (row & 7)) * 8));
      s_prev[mb] = __builtin_amdgcn_mfma_f32_16x16x32_bf16(kf, a_q[kc], s_prev[mb], 0, 0, 0);
    }
  }
  __builtin_amdgcn_s_setprio(0);

  f32x4 accO[16];  // O^T C-layout: ch = cb*16 + quad*4 + r, query = w*16+l16
#pragma unroll
  for (int cb = 0; cb < 16; ++cb) accO[cb] = (f32x4){0.f, 0.f, 0.f, 0.f};
  float m_run = -1e30f, l_run = 0.f;
  int pc0 = quad ^ (l16 & 7);        // V chunk for key-group 0 (loop-invariant)
  int pc1 = (4 + quad) ^ (l16 & 7);  // key-group 1

#pragma unroll 1
  for (int t = 0; t < TILES_PER_PART; ++t) {
    __syncthreads();  // DMA(issued last iter) complete; buffers' readers done
    short* Kd = (t & 1) ? Ks1 : Ks0;   // dest for K(t+2)
    short* Kr = (t & 1) ? Ks0 : Ks1;   // source for QK(t+1)
    short* Vd = (t & 1) ? Vs0 : Vs1;   // dest for V(t+1)
    short* Vr = (t & 1) ? Vs1 : Vs0;   // source for PV(t)
    if (t + 2 < TILES_PER_PART) {      // K-DMA(t+2): last read by QK(t) prev iter
      const char* kp = (const char*)(kb + (size_t)(mbase + (t + 2) * 64) * CCH);
#pragma unroll
      for (int i = 0; i < 4; ++i) {
        int off = tid * 16 + i * 8192;
        dma16(kp + off, (char*)Kd + off);
      }
    }
    if (t + 1 < TILES_PER_PART) {      // V-DMA(t+1): last read by PV(t-1)
      int m0 = mbase + (t + 1) * 64;
#pragma unroll
      for (int i = 0; i < 4; ++i) {
        int off = tid * 16 + i * 8192;
        int c = off >> 7, inrow = off & 127;
        dma16(vbB + (size_t)c * (NSP * 2) + (size_t)m0 * 2 + inrow,
              (char*)Vd + off);
      }
    }
    // ---- QK(t+1): independent MFMA stream, fills pipe under softmax(t) ----
    f32x4 sn[4];
#pragma unroll
    for (int mb = 0; mb < 4; ++mb) sn[mb] = (f32x4){0.f, 0.f, 0.f, 0.f};
    if (t + 1 < TILES_PER_PART) {
      __builtin_amdgcn_s_setprio(1);
#pragma unroll
      for (int kc = 0; kc < 8; ++kc) {
#pragma unroll
        for (int mb = 0; mb < 4; ++mb) {
          int row = mb * 16 + l16;
          bf16x8 kf = *(bf16x8*)(Kr + row * 256 + (((kc * 4 + quad) ^ (row & 7)) * 8));
          sn[mb] = __builtin_amdgcn_mfma_f32_16x16x32_bf16(kf, a_q[kc], sn[mb], 0, 0, 0);
        }
      }
      __builtin_amdgcn_s_setprio(0);
    }
    // ---- online softmax(t) on s_prev: per-lane scalar stats ----
    float mx = -1e30f;
#pragma unroll
    for (int mb = 0; mb < 4; ++mb)
#pragma unroll
      for (int r = 0; r < 4; ++r) mx = fmaxf(mx, s_prev[mb][r]);
    mx = fmaxf(mx, __shfl_xor(mx, 16));
    mx = fmaxf(mx, __shfl_xor(mx, 32));
    if (!__all(mx - m_run <= 8.f)) {   // T13: rescale only when max grows >8
      float mnew = fmaxf(m_run, mx);
      float alpha = __expf(m_run - mnew);
#pragma unroll
      for (int cb = 0; cb < 16; ++cb) accO[cb] *= alpha;
      l_run *= alpha;
      m_run = mnew;
    }
    float ls = 0.f;
#pragma unroll
    for (int mb = 0; mb < 4; ++mb)
#pragma unroll
      for (int r = 0; r < 4; ++r) {
        float p = __expf(s_prev[mb][r] - m_run);   // bounded by e^8
        ls += p;
        s_prev[mb][r] = p;
      }
    ls += __shfl_xor(ls, 16);
    ls += __shfl_xor(ls, 32);
    l_run += ls;
    // ---- pack P into 16x16x32 B-frags (key permutation makes this direct) --
    union { unsigned u[4]; bf16x8 v; } pw0, pw1;
    pw0.u[0] = cvt_pk_bf16(s_prev[0][0], s_prev[0][1]);
    pw0.u[1] = cvt_pk_bf16(s_prev[0][2], s_prev[0][3]);
    pw0.u[2] = cvt_pk_bf16(s_prev[2][0], s_prev[2][1]);
    pw0.u[3] = cvt_pk_bf16(s_prev[2][2], s_prev[2][3]);
    pw1.u[0] = cvt_pk_bf16(s_prev[1][0], s_prev[1][1]);
    pw1.u[1] = cvt_pk_bf16(s_prev[1][2], s_prev[1][3]);
    pw1.u[2] = cvt_pk_bf16(s_prev[3][0], s_prev[3][1]);
    pw1.u[3] = cvt_pk_bf16(s_prev[3][2], s_prev[3][3]);
    // ---- O^T += V P^T : full-rate 16x16x32, b128 V reads ----
    __builtin_amdgcn_s_setprio(1);
#pragma unroll
    for (int cb = 0; cb < 16; ++cb) {
      bf16x8 vf = *(bf16x8*)(Vr + (cb * 16 + l16) * 64 + pc0 * 8);
      accO[cb] = __builtin_amdgcn_mfma_f32_16x16x32_bf16(vf, pw0.v, accO[cb], 0, 0, 0);
    }
#pragma unroll
    for (int cb = 0; cb < 16; ++cb) {
      bf16x8 vf = *(bf16x8*)(Vr + (cb * 16 + l16) * 64 + pc1 * 8);
      accO[cb] = __builtin_amdgcn_mfma_f32_16x16x32_bf16(vf, pw1.v, accO[cb], 0, 0, 0);
    }
    __builtin_amdgcn_s_setprio(0);
    // ---- roll S ----
#pragma unroll
    for (int mb = 0; mb < 4; ++mb) s_prev[mb] = sn[mb];
  }
  // ---- stats ----
  size_t sbase = ((size_t)kh * BB + b) * NSP + n0;
  if (quad == 0) {
    pm[sbase + w * 16 + l16] = m_run;
    pl[sbase + w * 16 + l16] = l_run;
  }
  // ---- epilogue: normalized bf16 O -> po [kh][b][n][c], LDS transpose ----
  float linv = 1.f / l_run;
  short* ob = po + ((size_t)kh * BB + b) * NSP * CCH;
#pragma unroll
  for (int p = 0; p < 2; ++p) {
    __syncthreads();
    if ((w >> 2) == p) {
      int nloc = (w & 3) * 16 + l16;
#pragma unroll
      for (int cb = 0; cb < 16; ++cb)
#pragma unroll
        for (int r = 0; r < 4; ++r)
          Fo[nloc * 264 + cb * 16 + quad * 4 + r] = f2bf(accO[cb][r] * linv);
    }
    __syncthreads();
    int row = tid >> 3, seg = tid & 7;
    short* dst = ob + (size_t)(n0 + p * 64 + row) * CCH + seg * 32;
#pragma unroll
    for (int i = 0; i < 4; ++i)
      *(bf16x8*)(dst + i * 8) = *(bf16x8*)(Fo + row * 264 + seg * 32 + i * 8);
  }
}

// ------- proj: frag-direct MFMA, KSPLIT-way merge, n-block=32, 4 blk/CU ----
// 256 threads / 4 waves: wave = (ng = w&1 n-group of 16) x (hq = w>>1
// d-quarter of 64 within the block's 128-d range).
__global__ __launch_bounds__(256) void proj_kernel(
    const short* __restrict__ po, const float* __restrict__ pm,
    const float* __restrict__ pl, const short* __restrict__ wpt,
    const float* __restrict__ bp, const float* __restrict__ x,
    float* __restrict__ out) {
  int n0 = blockIdx.x * 32;
  int dh = blockIdx.y * 128;
  int b = blockIdx.z;
  int tid = threadIdx.x;
  int w = tid >> 6, lane = tid & 63, quad = lane >> 4, l16 = lane & 15;
  int ng = w & 1, hq = w >> 1;
  int n = n0 + ng * 16 + l16;
  int dbase = dh + hq * 64;

  float wgt[KSPLIT];
  {
    float m[KSPLIT];
    float M = -1e30f;
#pragma unroll
    for (int s = 0; s < KSPLIT; ++s) {
      m[s] = pm[((size_t)s * BB + b) * NSP + n];
      M = fmaxf(M, m[s]);
    }
    float wsum = 0.f;
#pragma unroll
    for (int s = 0; s < KSPLIT; ++s) {
      wgt[s] = __expf(m[s] - M) * pl[((size_t)s * BB + b) * NSP + n];
      wsum += wgt[s];
    }
    float linv = 1.f / wsum;
#pragma unroll
    for (int s = 0; s < KSPLIT; ++s) wgt[s] *= linv;
  }

  f32x4 acc[4];
#pragma unroll
  for (int mb = 0; mb < 4; ++mb) acc[mb] = (f32x4){0.f, 0.f, 0.f, 0.f};

  const short* pob = po + ((size_t)b * NSP + n) * CCH;
#pragma unroll 2
  for (int kc = 0; kc < 8; ++kc) {
    int coff = kc * 32 + quad * 8;
    float e[8];
#pragma unroll
    for (int i = 0; i < 8; ++i) e[i] = 0.f;
#pragma unroll
    for (int s = 0; s < KSPLIT; ++s) {
      bf16x8 f = *(const bf16x8*)(pob + (size_t)s * BB * NSP * CCH + coff);
#pragma unroll
      for (int i = 0; i < 8; ++i) e[i] += wgt[s] * bf2f(f[i]);
    }
    bf16x8 bm;
#pragma unroll
    for (int i = 0; i < 8; ++i) bm[i] = f2bf(e[i]);
#pragma unroll
    for (int mb = 0; mb < 4; ++mb) {
      bf16x8 af = *(const bf16x8*)(wpt + (size_t)(dbase + mb * 16 + l16) * CCH + coff);
      acc[mb] = __builtin_amdgcn_mfma_f32_16x16x32_bf16(af, bm, acc[mb], 0, 0, 0);
    }
  }
#pragma unroll
  for (int mb = 0; mb < 4; ++mb) {
#pragma unroll
    for (int r = 0; r < 4; ++r) {
      int d = dbase + mb * 16 + quad * 4 + r;
      size_t off = ((size_t)b * CCH + d) * NSP + n;
      out[off] = (acc[mb][r] + bp[d] + x[off]) * RSQRT2;
    }
  }
}

extern "C" void kernel_launch(void* const* d_in, const int* in_sizes, int n_in,
                              void* d_out, int out_size, void* d_ws, size_t ws_size,
                              hipStream_t stream) {
  const float* x  = (const float*)d_in[0];
  const float* gw = (const float*)d_in[1];
  const float* gb = (const float*)d_in[2];
  const float* Wq = (const float*)d_in[3];
  const float* bq = (const float*)d_in[4];
  const float* Wk = (const float*)d_in[5];
  const float* bk = (const float*)d_in[6];
  const float* Wv = (const float*)d_in[7];
  const float* bv = (const float*)d_in[8];
  const float* Wp = (const float*)d_in[9];
  const float* bp = (const float*)d_in[10];
  float* out = (float*)d_out;

  const size_t SZ = (size_t)BB * CCH * NSP;  // 4.19M elems
  short* qb  = (short*)d_ws;                 // bf16 [b][n][c] swizzled, scaled
  short* kb  = qb + SZ;                      // bf16 [b][n][c] swizzled
  short* vb  = kb + SZ;                      // bf16 [b][c][n] permuted
  short* poT = vb + SZ;                      // bf16 [KSPLIT][b][n][c] normalized
  float* pm  = (float*)(poT + (size_t)KSPLIT * SZ);  // [KSPLIT][b][n]
  float* pl  = pm + (size_t)KSPLIT * BB * NSP;
  float* stats = pl + (size_t)KSPLIT * BB * NSP;     // [b][32][2 half][2] raw
  short* wts = (short*)(stats + BB * 128);           // bf16 [4][256][256]
  short* wqt = wts;
  short* wkt = wts + (size_t)CCH * CCH;
  short* wvt = wts + (size_t)2 * CCH * CCH;
  short* wpt = wts + (size_t)3 * CCH * CCH;

  prep_all<<<dim3(320), dim3(256), 0, stream>>>(x, Wq, Wk, Wv, Wp, stats, wts);
  qkvg_kernel<<<dim3(512), dim3(256), 0, stream>>>(
      x, stats, gw, gb, wqt, wkt, wvt, bq, bk, bv, qb, kb, vb);
  attn_kernel<<<dim3(BB * 32 * KSPLIT), dim3(512), 0, stream>>>(
      qb, kb, vb, poT, pm, pl);
  proj_kernel<<<dim3(128, 2, BB), dim3(256), 0, stream>>>(
      poT, pm, pl, wpt, bp, x, out);
}

// Round 11
// 257.513 us; speedup vs baseline: 1.2375x; 1.0315x over previous
//
#include <hip/hip_runtime.h>
#include <math.h>

// AttnBlock: GroupNorm(32) -> q,k,v 1x1 -> spatial attention -> proj -> resid.
// Round 20: kill the 8x poT read amplification in proj. poT moves from
// [kh][b][n][c] to chunk-major [kh][b][ch=c/8][n][8]: attn's epilogue (already
// LDS-transposed via Fo) writes it with identical coalescing, and proj's
// per-lane row gather becomes 256B-contiguous per quad (was 8B used per 64B
// line, 64 strided rows per instruction ~ 134MB of wasted fetch ~ 18-21us).
// Everything else = R19 (attn 8-wave pipelined 96.9us, qkvg 512-blk TLP,
// proj 1024-blk, prep_all merged). R19 lesson ledgered: non-attn kernels are
// NOT occupancy-bound (2x TLP = noise); data-path waste is the lever.

#define BB 4
#define CCH 256
#define NSP 4096
#define EPSV 1e-5f
#define ATTN_SCALE 0.0625f  // 256^-0.5
#define RSQRT2 0.70710678118654752440f
#define KSPLIT 2
#define TILES_PER_PART 32   // 4096 / 64 / KSPLIT

typedef __attribute__((ext_vector_type(8))) short bf16x8;
typedef __attribute__((ext_vector_type(4))) float f32x4;

typedef __attribute__((address_space(1))) void gvoid;
typedef __attribute__((address_space(3))) void lvoid;
__device__ __forceinline__ void dma16(const void* g, void* l) {
  __builtin_amdgcn_global_load_lds((gvoid*)g, (lvoid*)l, 16, 0, 0);
}

__device__ __forceinline__ short f2bf(float f) {
  union { float f; unsigned u; } a; a.f = f;
  unsigned r = a.u + 0x7fffu + ((a.u >> 16) & 1u);  // RTN-even
  return (short)(r >> 16);
}
__device__ __forceinline__ float bf2f(short s) {
  union { unsigned u; float f; } a;
  a.u = ((unsigned)(unsigned short)s) << 16;
  return a.f;
}
__device__ __forceinline__ unsigned cvt_pk_bf16(float lo, float hi) {
  unsigned r;
  asm("v_cvt_pk_bf16_f32 %0, %1, %2" : "=v"(r) : "v"(lo), "v"(hi));
  return r;
}

// ---- prep_all: GN partial stats (blocks 0..255) + W transpose (256..319) ---
__global__ __launch_bounds__(256) void prep_all(
    const float* __restrict__ x,
    const float* __restrict__ Wq, const float* __restrict__ Wk,
    const float* __restrict__ Wv, const float* __restrict__ Wp,
    float* __restrict__ stats, short* __restrict__ wts) {
  __shared__ float T[64][65];
  int bid = blockIdx.x;
  int tid = threadIdx.x;
  if (bid < 256) {
    int b = bid >> 6, g = (bid >> 1) & 31, h = bid & 1;
    size_t base = ((size_t)b * CCH + (size_t)g * 8 + (size_t)h * 4) * NSP;
    const float4* xv = (const float4*)(x + base);
    float s = 0.f, ss = 0.f;
    for (int i = tid; i < 4096; i += 256) {
      float4 v = xv[i];
      s += (v.x + v.y) + (v.z + v.w);
      ss += (v.x * v.x + v.y * v.y) + (v.z * v.z + v.w * v.w);
    }
#pragma unroll
    for (int off = 32; off > 0; off >>= 1) {
      s += __shfl_down(s, off, 64);
      ss += __shfl_down(ss, off, 64);
    }
    int wv = tid >> 6;
    if ((tid & 63) == 0) { T[0][wv] = s; T[0][4 + wv] = ss; }
    __syncthreads();
    if (tid == 0) {
      float S = T[0][0] + T[0][1] + T[0][2] + T[0][3];
      float SS = T[0][4] + T[0][5] + T[0][6] + T[0][7];
      stats[((b * 32 + g) * 2 + h) * 2 + 0] = S;
      stats[((b * 32 + g) * 2 + h) * 2 + 1] = SS;
    }
  } else {
    int wid = bid - 256;
    int c0 = (wid & 3) * 64, d0 = ((wid >> 2) & 3) * 64;
    int wz = wid >> 4;
    const float* W = (wz == 0) ? Wq : (wz == 1) ? Wk : (wz == 2) ? Wv : Wp;
    short* wt = wts + (size_t)wz * CCH * CCH;
#pragma unroll
    for (int i = 0; i < 16; ++i) {
      int idx = tid + 256 * i;
      int row = idx >> 6, col = idx & 63;
      T[row][col] = W[(size_t)(c0 + row) * CCH + d0 + col];
    }
    __syncthreads();
#pragma unroll
    for (int i = 0; i < 16; ++i) {
      int idx = tid + 256 * i;
      int dr = idx >> 6, cc = idx & 63;
      wt[(size_t)(d0 + dr) * CCH + c0 + cc] = f2bf(T[cc][dr]);
    }
  }
}

// ------- qkvg: fused GN-apply + q,k,v projections via bf16 MFMA -----------
// n-block = 32, grid 512 = 2 independent blocks/CU. 256 threads / 4 waves:
// wave w: wr = w&1 (n-group of 16), h = w>>1 (d-half of 128).
__global__ __launch_bounds__(256) void qkvg_kernel(
    const float* __restrict__ x, const float* __restrict__ stats,
    const float* __restrict__ gw, const float* __restrict__ gb,
    const short* __restrict__ wqt, const short* __restrict__ wkt,
    const short* __restrict__ wvt,
    const float* __restrict__ bq, const float* __restrict__ bk,
    const float* __restrict__ bv,
    short* __restrict__ qo, short* __restrict__ ko, short* __restrict__ vo) {
  __shared__ __align__(16) unsigned char smem[26880];
  float* aco = (float*)smem;                      // 256 f32
  float* bco = aco + 256;                         // 256 f32
  float (*Ts)[33] = (float(*)[33])(smem + 2048);  // 64 x 33 fp32 (8448 B)
  short* Hs = (short*)(smem + 10496);             // [32 n][256 c] swizzled
  short* Fo = (short*)(smem + 2048);              // epilogue [32 n][264] bf16

  int bx = blockIdx.x;
  int b = bx & 3, n0 = (bx >> 2) * 32;
  int tid = threadIdx.x;
  {  // per-channel scale/shift (combine 2 GN partials)
    int g = tid >> 3;
    const float* sp = stats + (size_t)(b * 32 + g) * 4;
    float S = sp[0] + sp[2], SS = sp[1] + sp[3];
    float mean = S * (1.f / 32768.f);
    float var = SS * (1.f / 32768.f) - mean * mean;
    float rstd = rsqrtf(var + EPSV);
    float a = gw[tid] * rstd;
    aco[tid] = a;
    bco[tid] = gb[tid] - mean * a;
  }
  __syncthreads();
  const float* xb = x + (size_t)b * CCH * NSP;
  // ---- 4 passes: load x chunk (64c x 32n), normalize, transpose -> Hs ----
  for (int p = 0; p < 4; ++p) {
    int c0 = p * 64;
#pragma unroll
    for (int i = 0; i < 2; ++i) {
      int crow = (tid >> 3) + i * 32;
      int c = c0 + crow;
      float4 v = *(const float4*)&xb[(size_t)c * NSP + n0 + (tid & 7) * 4];
      float a = aco[c], bb = bco[c];
      v.x = v.x * a + bb; v.y = v.y * a + bb;
      v.z = v.z * a + bb; v.w = v.w * a + bb;
      *(float4*)&Ts[crow][(tid & 7) * 4] = v;   // Ts[c_local][n_local]
    }
    __syncthreads();
    {
      int n = tid >> 3, seg = tid & 7;
      int cb = seg * 8;
      bf16x8 r;
#pragma unroll
      for (int j = 0; j < 8; ++j) r[j] = f2bf(Ts[cb + j][n]);
      int chunk = p * 8 + seg;
      *(bf16x8*)(Hs + n * 256 + ((chunk ^ (n & 7)) * 8)) = r;
    }
    __syncthreads();
  }
  // ---- extract B-frags (rows = this wave's 16 n; shared across h) ----
  int w = tid >> 6, lane = tid & 63, quad = lane >> 4, l16 = lane & 15;
  int wr = w & 1, h = w >> 1;  // n-group, d-half
  bf16x8 a_h[8];
  {
    int row = wr * 16 + l16;
#pragma unroll
    for (int kc = 0; kc < 8; ++kc)
      a_h[kc] = *(bf16x8*)(Hs + row * 256 + (((kc * 4 + quad) ^ (row & 7)) * 8));
  }
  __syncthreads();  // all waves extracted; smem reusable as Fo
  // ---- 3 projections; wave handles d in [h*128, h*128+128) ----
  for (int op = 0; op < 3; ++op) {
    const short* wt = (op == 0) ? wqt : (op == 1) ? wkt : wvt;
    const float* bias = (op == 0) ? bq : (op == 1) ? bk : bv;
    f32x4 acc[8];
#pragma unroll
    for (int mb = 0; mb < 8; ++mb) acc[mb] = (f32x4){0.f, 0.f, 0.f, 0.f};
#pragma unroll 4
    for (int mb = 0; mb < 8; ++mb) {
      const short* wp = wt + (size_t)((h * 8 + mb) * 16 + l16) * CCH + quad * 8;
#pragma unroll
      for (int kc = 0; kc < 8; ++kc) {
        bf16x8 af = *(const bf16x8*)(wp + kc * 32);
        acc[mb] = __builtin_amdgcn_mfma_f32_16x16x32_bf16(af, a_h[kc], acc[mb], 0, 0, 0);
      }
    }
    int n = n0 + wr * 16 + l16;
    if (op == 2) {  // v: [c][n-permuted] scalar stores (global-n formulas)
      short* ob = vo + (size_t)b * CCH * NSP;
      int mm = n & 63, m0_ = n & ~63;
      int mb_ = mm >> 4, qq = (mm >> 2) & 3, rr2 = mm & 3;
      int lc = (mb_ & 1) * 4 + qq;          // logical 8-key chunk
      int jj = (mb_ >> 1) * 4 + rr2;        // slot within chunk
      int basen = m0_ + jj;
#pragma unroll
      for (int mb = 0; mb < 8; ++mb)
#pragma unroll
        for (int r = 0; r < 4; ++r) {
          int d = (h * 8 + mb) * 16 + quad * 4 + r;
          ob[(size_t)d * NSP + basen + ((lc ^ (d & 7)) << 3)] =
              f2bf(acc[mb][r] + bias[d]);
        }
    } else {  // q/k: transpose via Fo -> [n][c] b128 stores, chunk-swizzled
      float sc = (op == 0) ? ATTN_SCALE : 1.f;
      int nl = wr * 16 + l16;
#pragma unroll
      for (int mb = 0; mb < 8; ++mb)
#pragma unroll
        for (int r = 0; r < 4; ++r) {
          int d = (h * 8 + mb) * 16 + quad * 4 + r;
          Fo[nl * 264 + d] = f2bf((acc[mb][r] + bias[d]) * sc);
        }
      __syncthreads();
      short* ob = ((op == 0) ? qo : ko) + (size_t)b * NSP * CCH;
      {
        int row = tid >> 3, seg = tid & 7, r7 = row & 7;  // row 0..31
        short* dst = ob + (size_t)(n0 + row) * CCH + seg * 32;
#pragma unroll
        for (int i = 0; i < 4; ++i) {
          int xch = seg * 4 + i;
          int cs = (xch & 24) | ((xch & 7) ^ r7);  // source chunk for slot xch
          *(bf16x8*)(dst + i * 8) = *(bf16x8*)(Fo + row * 264 + cs * 8);
        }
      }
      __syncthreads();
    }
  }
}

// ------ flash attention: 8 waves, 16 q/wave, 128 q/block, pipelined --------
// R13/round-4 structure. K,V double-buffered (128 KiB LDS); one barrier per
// tile; QK(t+1) overlaps softmax(t)+PV(t). Epilogue writes poT chunk-major:
// po2[kh][b][ch][n][8] (ch = c/8) so proj's reads are contiguous.
__global__ __launch_bounds__(512, 1) void attn_kernel(
    const short* __restrict__ q, const short* __restrict__ k,
    const short* __restrict__ v, short* __restrict__ po,
    float* __restrict__ pm, float* __restrict__ pl) {
  __shared__ __align__(16) unsigned char smem[131072];  // 128 KB
  short* Ks0 = (short*)smem;             // K even tiles / Q stage
  short* Ks1 = (short*)(smem + 32768);   // K odd tiles
  short* Vs0 = (short*)(smem + 65536);   // V even tiles
  short* Vs1 = (short*)(smem + 98304);   // V odd tiles
  short* Fo  = (short*)smem;             // epilogue [64 n][264 c] bf16

  int bx = blockIdx.x;
  int b = bx & 3;
  int n0 = ((bx >> 2) & 31) << 7;   // 128-query block
  int kh = bx >> 7;                 // key half
  const short* qb = q + (size_t)b * NSP * CCH;
  const short* kb = k + (size_t)b * NSP * CCH;
  const char*  vbB = (const char*)(v + (size_t)b * CCH * NSP);
  int tid = threadIdx.x;
  int w = tid >> 6, lane = tid & 63, quad = lane >> 4, l16 = lane & 15;
  int mbase = kh * TILES_PER_PART * 64;

  // ---- stage Q in 2 passes of 64 rows through Ks0; extract B-frags ----
  bf16x8 a_q[8];
#pragma unroll
  for (int p = 0; p < 2; ++p) {
#pragma unroll
    for (int i = 0; i < 4; ++i) {
      int off = tid * 16 + i * 8192;
      dma16((const char*)(qb + (size_t)(n0 + p * 64) * CCH) + off,
            (char*)Ks0 + off);
    }
    __syncthreads();
    if ((w >> 2) == p) {
      int row = (w & 3) * 16 + l16;
#pragma unroll
      for (int kc = 0; kc < 8; ++kc)
        a_q[kc] = *(bf16x8*)(Ks0 + row * 256 + (((kc * 4 + quad) ^ (row & 7)) * 8));
    }
    __syncthreads();
  }

  // ---- prologue: K0->Ks0, V0->Vs0; drain; K1->Ks1; QK(0) ----
#pragma unroll
  for (int i = 0; i < 4; ++i) {
    int off = tid * 16 + i * 8192;
    dma16((const char*)(kb + (size_t)mbase * CCH) + off, (char*)Ks0 + off);
    int c = off >> 7, inrow = off & 127;
    dma16(vbB + (size_t)c * (NSP * 2) + (size_t)mbase * 2 + inrow,
          (char*)Vs0 + off);
  }
  __syncthreads();
#pragma unroll
  for (int i = 0; i < 4; ++i) {
    int off = tid * 16 + i * 8192;
    dma16((const char*)(kb + (size_t)(mbase + 64) * CCH) + off,
          (char*)Ks1 + off);
  }
  f32x4 s_prev[4];
#pragma unroll
  for (int mb = 0; mb < 4; ++mb) s_prev[mb] = (f32x4){0.f, 0.f, 0.f, 0.f};
  __builtin_amdgcn_s_setprio(1);
#pragma unroll
  for (int kc = 0; kc < 8; ++kc) {
#pragma unroll
    for (int mb = 0; mb < 4; ++mb) {
      int row = mb * 16 + l16;
      bf16x8 kf = *(bf16x8*)(Ks0 + row * 256 + (((kc * 4 + quad) ^ (row & 7)) * 8));
      s_prev[mb] = __builtin_amdgcn_mfma_f32_16x16x32_bf16(kf, a_q[kc], s_prev[mb], 0, 0, 0);
    }
  }
  __builtin_amdgcn_s_setprio(0);

  f32x4 accO[16];  // O^T C-layout: ch = cb*16 + quad*4 + r, query = w*16+l16
#pragma unroll
  for (int cb = 0; cb < 16; ++cb) accO[cb] = (f32x4){0.f, 0.f, 0.f, 0.f};
  float m_run = -1e30f, l_run = 0.f;
  int pc0 = quad ^ (l16 & 7);        // V chunk for key-group 0 (loop-invariant)
  int pc1 = (4 + quad) ^ (l16 & 7);  // key-group 1

#pragma unroll 1
  for (int t = 0; t < TILES_PER_PART; ++t) {
    __syncthreads();  // DMA(issued last iter) complete; buffers' readers done
    short* Kd = (t & 1) ? Ks1 : Ks0;   // dest for K(t+2)
    short* Kr = (t & 1) ? Ks0 : Ks1;   // source for QK(t+1)
    short* Vd = (t & 1) ? Vs0 : Vs1;   // dest for V(t+1)
    short* Vr = (t & 1) ? Vs1 : Vs0;   // source for PV(t)
    if (t + 2 < TILES_PER_PART) {      // K-DMA(t+2): last read by QK(t) prev iter
      const char* kp = (const char*)(kb + (size_t)(mbase + (t + 2) * 64) * CCH);
#pragma unroll
      for (int i = 0; i < 4; ++i) {
        int off = tid * 16 + i * 8192;
        dma16(kp + off, (char*)Kd + off);
      }
    }
    if (t + 1 < TILES_PER_PART) {      // V-DMA(t+1): last read by PV(t-1)
      int m0 = mbase + (t + 1) * 64;
#pragma unroll
      for (int i = 0; i < 4; ++i) {
        int off = tid * 16 + i * 8192;
        int c = off >> 7, inrow = off & 127;
        dma16(vbB + (size_t)c * (NSP * 2) + (size_t)m0 * 2 + inrow,
              (char*)Vd + off);
      }
    }
    // ---- QK(t+1): independent MFMA stream, fills pipe under softmax(t) ----
    f32x4 sn[4];
#pragma unroll
    for (int mb = 0; mb < 4; ++mb) sn[mb] = (f32x4){0.f, 0.f, 0.f, 0.f};
    if (t + 1 < TILES_PER_PART) {
      __builtin_amdgcn_s_setprio(1);
#pragma unroll
      for (int kc = 0; kc < 8; ++kc) {
#pragma unroll
        for (int mb = 0; mb < 4; ++mb) {
          int row = mb * 16 + l16;
          bf16x8 kf = *(bf16x8*)(Kr + row * 256 + (((kc * 4 + quad) ^ (row & 7)) * 8));
          sn[mb] = __builtin_amdgcn_mfma_f32_16x16x32_bf16(kf, a_q[kc], sn[mb], 0, 0, 0);
        }
      }
      __builtin_amdgcn_s_setprio(0);
    }
    // ---- online softmax(t) on s_prev: per-lane scalar stats ----
    float mx = -1e30f;
#pragma unroll
    for (int mb = 0; mb < 4; ++mb)
#pragma unroll
      for (int r = 0; r < 4; ++r) mx = fmaxf(mx, s_prev[mb][r]);
    mx = fmaxf(mx, __shfl_xor(mx, 16));
    mx = fmaxf(mx, __shfl_xor(mx, 32));
    if (!__all(mx - m_run <= 8.f)) {   // T13: rescale only when max grows >8
      float mnew = fmaxf(m_run, mx);
      float alpha = __expf(m_run - mnew);
#pragma unroll
      for (int cb = 0; cb < 16; ++cb) accO[cb] *= alpha;
      l_run *= alpha;
      m_run = mnew;
    }
    float ls = 0.f;
#pragma unroll
    for (int mb = 0; mb < 4; ++mb)
#pragma unroll
      for (int r = 0; r < 4; ++r) {
        float p = __expf(s_prev[mb][r] - m_run);   // bounded by e^8
        ls += p;
        s_prev[mb][r] = p;
      }
    ls += __shfl_xor(ls, 16);
    ls += __shfl_xor(ls, 32);
    l_run += ls;
    // ---- pack P into 16x16x32 B-frags (key permutation makes this direct) --
    union { unsigned u[4]; bf16x8 v; } pw0, pw1;
    pw0.u[0] = cvt_pk_bf16(s_prev[0][0], s_prev[0][1]);
    pw0.u[1] = cvt_pk_bf16(s_prev[0][2], s_prev[0][3]);
    pw0.u[2] = cvt_pk_bf16(s_prev[2][0], s_prev[2][1]);
    pw0.u[3] = cvt_pk_bf16(s_prev[2][2], s_prev[2][3]);
    pw1.u[0] = cvt_pk_bf16(s_prev[1][0], s_prev[1][1]);
    pw1.u[1] = cvt_pk_bf16(s_prev[1][2], s_prev[1][3]);
    pw1.u[2] = cvt_pk_bf16(s_prev[3][0], s_prev[3][1]);
    pw1.u[3] = cvt_pk_bf16(s_prev[3][2], s_prev[3][3]);
    // ---- O^T += V P^T : full-rate 16x16x32, b128 V reads ----
    __builtin_amdgcn_s_setprio(1);
#pragma unroll
    for (int cb = 0; cb < 16; ++cb) {
      bf16x8 vf = *(bf16x8*)(Vr + (cb * 16 + l16) * 64 + pc0 * 8);
      accO[cb] = __builtin_amdgcn_mfma_f32_16x16x32_bf16(vf, pw0.v, accO[cb], 0, 0, 0);
    }
#pragma unroll
    for (int cb = 0; cb < 16; ++cb) {
      bf16x8 vf = *(bf16x8*)(Vr + (cb * 16 + l16) * 64 + pc1 * 8);
      accO[cb] = __builtin_amdgcn_mfma_f32_16x16x32_bf16(vf, pw1.v, accO[cb], 0, 0, 0);
    }
    __builtin_amdgcn_s_setprio(0);
    // ---- roll S ----
#pragma unroll
    for (int mb = 0; mb < 4; ++mb) s_prev[mb] = sn[mb];
  }
  // ---- stats ----
  size_t sbase = ((size_t)kh * BB + b) * NSP + n0;
  if (quad == 0) {
    pm[sbase + w * 16 + l16] = m_run;
    pl[sbase + w * 16 + l16] = l_run;
  }
  // ---- epilogue: normalized bf16 O -> po2 [kh][b][ch][n][8] chunk-major ----
  float linv = 1.f / l_run;
  short* ob = po + ((size_t)kh * BB + b) * NSP * CCH;
#pragma unroll
  for (int p = 0; p < 2; ++p) {
    __syncthreads();
    if ((w >> 2) == p) {
      int nloc = (w & 3) * 16 + l16;
#pragma unroll
      for (int cb = 0; cb < 16; ++cb)
#pragma unroll
        for (int r = 0; r < 4; ++r)
          Fo[nloc * 264 + cb * 16 + quad * 4 + r] = f2bf(accO[cb][r] * linv);
    }
    __syncthreads();
    int row = tid >> 3, seg = tid & 7;
    int n = n0 + p * 64 + row;
#pragma unroll
    for (int i = 0; i < 4; ++i) {
      int ch = seg * 4 + i;
      *(bf16x8*)(ob + ((size_t)ch * NSP + n) * 8) =
          *(bf16x8*)(Fo + row * 264 + ch * 8);
    }
  }
}

// ------- proj: frag-direct MFMA, KSPLIT-way merge, chunk-major poT reads ---
// 256 threads / 4 waves: wave = (ng = w&1 n-group of 16) x (hq = w>>1
// d-quarter of 64 within the block's 128-d range).
__global__ __launch_bounds__(256) void proj_kernel(
    const short* __restrict__ po, const float* __restrict__ pm,
    const float* __restrict__ pl, const short* __restrict__ wpt,
    const float* __restrict__ bp, const float* __restrict__ x,
    float* __restrict__ out) {
  int n0 = blockIdx.x * 32;
  int dh = blockIdx.y * 128;
  int b = blockIdx.z;
  int tid = threadIdx.x;
  int w = tid >> 6, lane = tid & 63, quad = lane >> 4, l16 = lane & 15;
  int ng = w & 1, hq = w >> 1;
  int n = n0 + ng * 16 + l16;
  int dbase = dh + hq * 64;

  float wgt[KSPLIT];
  {
    float m[KSPLIT];
    float M = -1e30f;
#pragma unroll
    for (int s = 0; s < KSPLIT; ++s) {
      m[s] = pm[((size_t)s * BB + b) * NSP + n];
      M = fmaxf(M, m[s]);
    }
    float wsum = 0.f;
#pragma unroll
    for (int s = 0; s < KSPLIT; ++s) {
      wgt[s] = __expf(m[s] - M) * pl[((size_t)s * BB + b) * NSP + n];
      wsum += wgt[s];
    }
    float linv = 1.f / wsum;
#pragma unroll
    for (int s = 0; s < KSPLIT; ++s) wgt[s] *= linv;
  }

  f32x4 acc[4];
#pragma unroll
  for (int mb = 0; mb < 4; ++mb) acc[mb] = (f32x4){0.f, 0.f, 0.f, 0.f};

#pragma unroll 2
  for (int kc = 0; kc < 8; ++kc) {
    int coff = kc * 32 + quad * 8;
    int ch = kc * 4 + quad;   // c-chunk index for chunk-major poT
    float e[8];
#pragma unroll
    for (int i = 0; i < 8; ++i) e[i] = 0.f;
#pragma unroll
    for (int s = 0; s < KSPLIT; ++s) {
      bf16x8 f = *(const bf16x8*)(po + ((size_t)s * BB + b) * NSP * CCH +
                                  ((size_t)ch * NSP + n) * 8);
#pragma unroll
      for (int i = 0; i < 8; ++i) e[i] += wgt[s] * bf2f(f[i]);
    }
    bf16x8 bm;
#pragma unroll
    for (int i = 0; i < 8; ++i) bm[i] = f2bf(e[i]);
#pragma unroll
    for (int mb = 0; mb < 4; ++mb) {
      bf16x8 af = *(const bf16x8*)(wpt + (size_t)(dbase + mb * 16 + l16) * CCH + coff);
      acc[mb] = __builtin_amdgcn_mfma_f32_16x16x32_bf16(af, bm, acc[mb], 0, 0, 0);
    }
  }
#pragma unroll
  for (int mb = 0; mb < 4; ++mb) {
#pragma unroll
    for (int r = 0; r < 4; ++r) {
      int d = dbase + mb * 16 + quad * 4 + r;
      size_t off = ((size_t)b * CCH + d) * NSP + n;
      out[off] = (acc[mb][r] + bp[d] + x[off]) * RSQRT2;
    }
  }
}

extern "C" void kernel_launch(void* const* d_in, const int* in_sizes, int n_in,
                              void* d_out, int out_size, void* d_ws, size_t ws_size,
                              hipStream_t stream) {
  const float* x  = (const float*)d_in[0];
  const float* gw = (const float*)d_in[1];
  const float* gb = (const float*)d_in[2];
  const float* Wq = (const float*)d_in[3];
  const float* bq = (const float*)d_in[4];
  const float* Wk = (const float*)d_in[5];
  const float* bk = (const float*)d_in[6];
  const float* Wv = (const float*)d_in[7];
  const float* bv = (const float*)d_in[8];
  const float* Wp = (const float*)d_in[9];
  const float* bp = (const float*)d_in[10];
  float* out = (float*)d_out;

  const size_t SZ = (size_t)BB * CCH * NSP;  // 4.19M elems
  short* qb  = (short*)d_ws;                 // bf16 [b][n][c] swizzled, scaled
  short* kb  = qb + SZ;                      // bf16 [b][n][c] swizzled
  short* vb  = kb + SZ;                      // bf16 [b][c][n] permuted
  short* poT = vb + SZ;                      // bf16 [KSPLIT][b][ch][n][8]
  float* pm  = (float*)(poT + (size_t)KSPLIT * SZ);  // [KSPLIT][b][n]
  float* pl  = pm + (size_t)KSPLIT * BB * NSP;
  float* stats = pl + (size_t)KSPLIT * BB * NSP;     // [b][32][2 half][2] raw
  short* wts = (short*)(stats + BB * 128);           // bf16 [4][256][256]
  short* wqt = wts;
  short* wkt = wts + (size_t)CCH * CCH;
  short* wvt = wts + (size_t)2 * CCH * CCH;
  short* wpt = wts + (size_t)3 * CCH * CCH;

  prep_all<<<dim3(320), dim3(256), 0, stream>>>(x, Wq, Wk, Wv, Wp, stats, wts);
  qkvg_kernel<<<dim3(512), dim3(256), 0, stream>>>(
      x, stats, gw, gb, wqt, wkt, wvt, bq, bk, bv, qb, kb, vb);
  attn_kernel<<<dim3(BB * 32 * KSPLIT), dim3(512), 0, stream>>>(
      qb, kb, vb, poT, pm, pl);
  proj_kernel<<<dim3(128, 2, BB), dim3(256), 0, stream>>>(
      poT, pm, pl, wpt, bp, x, out);
}